// Round 9
// baseline (191.784 us; speedup 1.0000x reference)
//
#include <hip/hip_runtime.h>
#include <cstdint>
#include <cstddef>

// Problem constants
// B=2, C=128, H=W=128, Hs=Ws=64, DG=8, KK=9, CG=16, COUT_DCN=64, HW=16384

typedef _Float16 f16x8 __attribute__((ext_vector_type(8)));
typedef _Float16 f16x4 __attribute__((ext_vector_type(4)));
typedef float    f32x4 __attribute__((ext_vector_type(4)));

__device__ __forceinline__ float relu_(float x) { return fmaxf(x, 0.f); }

// ---------------------------------------------------------------------------
// conv1x1 (fp32, LDS-tiled) — FALLBACK path only.
// ---------------------------------------------------------------------------
template<int MODE, int CIN>
__global__ __launch_bounds__(256) void conv1x1_kernel(
    const float* __restrict__ in1, const float* __restrict__ in2,
    const float* __restrict__ Wm, float* __restrict__ out)
{
  constexpr int IN1C = (MODE == 2) ? 64 : 128;
  const int b  = blockIdx.y;
  const int p0 = blockIdx.x * 64;
  const int tid = threadIdx.x;
  const int tx = tid & 7;
  const int ty = tid >> 3;

  __shared__ float Xs[16][64];
  __shared__ float Wt[16][128];

  float acc[4][8];
#pragma unroll
  for (int i = 0; i < 4; ++i)
#pragma unroll
    for (int j = 0; j < 8; ++j) acc[i][j] = 0.f;

  const int cS  = tid >> 4;
  const int pxS = (tid & 15) * 4;
  const int ocS = (tid & 15) * 8;

  for (int cc = 0; cc < CIN; cc += 16) {
    __syncthreads();
    {
      int gc = cc + cS;
      float4 v;
      if (MODE == 1 && gc >= 128) {
        int sc = gc - 128;
        float t[4];
#pragma unroll
        for (int j = 0; j < 4; ++j) {
          int pp = p0 + pxS + j;
          int hh = pp >> 7, ww = pp & 127;
          t[j] = 2.f * in2[((size_t)(b * 128 + sc) << 12) + ((hh >> 1) << 6) + (ww >> 1)];
        }
        v = make_float4(t[0], t[1], t[2], t[3]);
      } else {
        v = *(const float4*)(in1 + ((size_t)(b * IN1C + gc) << 14) + p0 + pxS);
      }
      *(float4*)&Xs[cS][pxS] = v;
#pragma unroll
      for (int j = 0; j < 8; ++j)
        Wt[cS][ocS + j] = Wm[(ocS + j) * CIN + cc + cS];
    }
    __syncthreads();
#pragma unroll
    for (int c = 0; c < 16; ++c) {
      float4 wv = *(const float4*)&Wt[c][ty * 4];
      float4 x0 = *(const float4*)&Xs[c][tx * 8];
      float4 x1 = *(const float4*)&Xs[c][tx * 8 + 4];
      float xs[8] = {x0.x, x0.y, x0.z, x0.w, x1.x, x1.y, x1.z, x1.w};
      float wf[4] = {wv.x, wv.y, wv.z, wv.w};
#pragma unroll
      for (int i = 0; i < 4; ++i)
#pragma unroll
        for (int j = 0; j < 8; ++j)
          acc[i][j] = fmaf(wf[i], xs[j], acc[i][j]);
    }
  }

#pragma unroll
  for (int i = 0; i < 4; ++i) {
    int oc = ty * 4 + i;
    size_t base = ((size_t)(b * 128 + oc) << 14) + p0 + tx * 8;
    float r[8];
#pragma unroll
    for (int j = 0; j < 8; ++j) r[j] = relu_(acc[i][j]);
    if (MODE == 2) {
#pragma unroll
      for (int j = 0; j < 8; ++j) r[j] += in2[base + j];
    }
    *(float4*)(out + base)     = make_float4(r[0], r[1], r[2], r[3]);
    *(float4*)(out + base + 4) = make_float4(r[4], r[5], r[6], r[7]);
  }
}

// ---------------------------------------------------------------------------
// t2h2: fused transpose of feat_l and feat_s: [b][128][HW] f32 -> [b][HW][128] f16
// ---------------------------------------------------------------------------
__global__ __launch_bounds__(256) void t2h2_kernel(
    const float* __restrict__ fl, const float* __restrict__ fs,
    _Float16* __restrict__ flTh, _Float16* __restrict__ fsTh)
{
  const int bx = blockIdx.x;
  const float* src;
  _Float16* dst;
  int HW, p0;
  if (bx < 512) { src = fl; dst = flTh; HW = 16384; p0 = bx * 32; }
  else          { src = fs; dst = fsTh; HW = 4096;  p0 = (bx - 512) * 32; }
  const int b  = blockIdx.z;
  const int c0 = blockIdx.y * 32;
  const int tid = threadIdx.x;
  __shared__ float T[32][33];
  {
    int pxl = tid & 31, cy = tid >> 5;
#pragma unroll
    for (int j = 0; j < 4; ++j) {
      int c = cy + j * 8;
      T[c][pxl] = src[((size_t)(b * 128 + c0 + c)) * HW + p0 + pxl];
    }
  }
  __syncthreads();
  {
    int cq = tid & 7, pr = tid >> 3;
    f16x4 v;
#pragma unroll
    for (int e = 0; e < 4; ++e) v[e] = (_Float16)T[cq * 4 + e][pr];
    *(f16x4*)&dst[(((size_t)b * HW) + p0 + pr) * 128 + c0 + cq * 4] = v;
  }
}

// ---------------------------------------------------------------------------
// wfall: all 5 weight packs in one launch. Block ranges:
// [0,8) WfA | [8,24) WfB | [24,168) WfP | [168,204) Wf2 | [204,208) WfC
// ---------------------------------------------------------------------------
__global__ __launch_bounds__(256) void wfall_kernel(
    const float* __restrict__ fsm_w, const float* __restrict__ offset_w,
    const float* __restrict__ com_w, const float* __restrict__ dcn_w,
    const float* __restrict__ cat_w,
    _Float16* __restrict__ WfA, _Float16* __restrict__ WfB,
    _Float16* __restrict__ WfP, _Float16* __restrict__ Wf2,
    _Float16* __restrict__ WfC)
{
  const int bid = blockIdx.x;
  if (bid < 8) {                         // WfA: fsm_w [128][128]
    int idx = bid * 256 + threadIdx.x;
    int lane = idx & 63;
    int t = idx >> 6;
    int m = t & 7, q = t >> 3;
    int oc = m * 16 + (lane & 15);
    int c0 = q * 32 + (lane >> 4) * 8;
    f16x8 v;
#pragma unroll
    for (int j = 0; j < 8; ++j) v[j] = (_Float16)fsm_w[oc * 128 + c0 + j];
    ((f16x8*)WfA)[idx] = v;
  } else if (bid < 24) {                 // WfB: offset_w [128][256], x2 on c>=128
    int idx = (bid - 8) * 256 + threadIdx.x;
    int lane = idx & 63;
    int t = idx >> 6;
    int m = t & 7, q = t >> 3;
    int oc = m * 16 + (lane & 15);
    int c0 = q * 32 + (lane >> 4) * 8;
    float s = (q >= 4) ? 2.f : 1.f;
    f16x8 v;
#pragma unroll
    for (int j = 0; j < 8; ++j) v[j] = (_Float16)(offset_w[oc * 256 + c0 + j] * s);
    ((f16x8*)WfB)[idx] = v;
  } else if (bid < 168) {                // WfP: com_w, oc-half-major, pad 256
    int idx = (bid - 24) * 256 + threadIdx.x;
    int lane = idx & 63;
    int t = idx >> 6;
    int m = t & 7;
    int t2 = t >> 3;
    int half = t2 & 1, q = t2 >> 1;
    int kk = q >> 2;
    int ic0 = (q & 3) * 32 + (lane >> 4) * 8;
    int oc = half * 128 + m * 16 + (lane & 15);
    f16x8 v;
#pragma unroll
    for (int j = 0; j < 8; ++j) {
      float x = (oc < 216) ? com_w[((size_t)oc * 128 + ic0 + j) * 9 + kk] : 0.f;
      v[j] = (_Float16)x;
    }
    ((f16x8*)WfP)[idx] = v;
  } else if (bid < 204) {                // Wf2: dcn_w, r' = (g*9+k)*16+c
    int idx = (bid - 168) * 256 + threadIdx.x;
    int lane = idx & 63;
    int t = idx >> 6;
    int m = t & 3, q = t >> 2;
    int oc = m * 16 + (lane & 15);
    f16x8 v;
#pragma unroll
    for (int j = 0; j < 8; ++j) {
      int rp = q * 32 + (lane >> 4) * 8 + j;
      int c = rp & 15, tt = rp >> 4;
      int g = tt / 9, k = tt % 9;
      v[j] = (_Float16)dcn_w[((size_t)oc * 128 + g * 16 + c) * 9 + k];
    }
    ((f16x8*)Wf2)[idx] = v;
  } else {                               // WfC: cat_w [128][64]
    int idx = (bid - 204) * 256 + threadIdx.x;
    int lane = idx & 63;
    int t = idx >> 6;
    int m = t & 7, q = t >> 3;
    int oc = m * 16 + (lane & 15);
    int k0 = q * 32 + (lane >> 4) * 8;
    f16x8 v;
#pragma unroll
    for (int j = 0; j < 8; ++j) v[j] = (_Float16)cat_w[oc * 64 + k0 + j];
    ((f16x8*)WfC)[idx] = v;
  }
}

// ---------------------------------------------------------------------------
// fsm GEMM: arm = relu(fsm_w @ feat_l). Outputs arm f32 [oc][p] + armh f16 [p][oc].
// ---------------------------------------------------------------------------
__global__ __launch_bounds__(256) void fsm_gemm_kernel(
    const _Float16* __restrict__ flTh, const _Float16* __restrict__ WfA,
    float* __restrict__ arm, _Float16* __restrict__ armh)
{
  const int b    = blockIdx.y;
  const int tid  = threadIdx.x;
  const int wv   = tid >> 6;
  const int lane = tid & 63;
  const int px0  = blockIdx.x * 64 + wv * 16;
  const int pxl  = px0 + (lane & 15);

  f32x4 acc[8];
#pragma unroll
  for (int m = 0; m < 8; ++m) acc[m] = (f32x4){0.f, 0.f, 0.f, 0.f};

  const f16x8* Bp = (const f16x8*)flTh + (((size_t)b << 14) + pxl) * 16 + (lane >> 4);
  const f16x8* Ap = (const f16x8*)WfA + lane;

#pragma unroll
  for (int q = 0; q < 4; ++q) {
    f16x8 bf = Bp[q * 4];
#pragma unroll
    for (int m = 0; m < 8; ++m)
      acc[m] = __builtin_amdgcn_mfma_f32_16x16x32_f16(Ap[(q * 8 + m) * 64], bf, acc[m], 0, 0, 0);
  }

  const int r0 = (lane >> 4) * 4;
#pragma unroll
  for (int m = 0; m < 8; ++m) {
    f16x4 h;
#pragma unroll
    for (int r = 0; r < 4; ++r) {
      float v = relu_(acc[m][r]);
      arm[((size_t)(b * 128 + m * 16 + r0 + r) << 14) + pxl] = v;
      h[r] = (_Float16)v;
    }
    *(f16x4*)&armh[(((size_t)b << 14) + pxl) * 128 + m * 16 + r0] = h;
  }
}

// ---------------------------------------------------------------------------
// offset GEMM: offh = relu(offset_w @ [armh ; 2*featup]) in f16 [p][128].
// ---------------------------------------------------------------------------
__global__ __launch_bounds__(256) void off_gemm_kernel(
    const _Float16* __restrict__ armh, const _Float16* __restrict__ fsTh,
    const _Float16* __restrict__ WfB, _Float16* __restrict__ offh)
{
  const int b    = blockIdx.y;
  const int tid  = threadIdx.x;
  const int wv   = tid >> 6;
  const int lane = tid & 63;
  const int px0  = blockIdx.x * 64 + wv * 16;
  const int pxl  = px0 + (lane & 15);
  const int h = pxl >> 7, w = pxl & 127;
  const int pup = ((h >> 1) << 6) + (w >> 1);

  f32x4 acc[8];
#pragma unroll
  for (int m = 0; m < 8; ++m) acc[m] = (f32x4){0.f, 0.f, 0.f, 0.f};

  const f16x8* BpA = (const f16x8*)armh + (((size_t)b << 14) + pxl) * 16 + (lane >> 4);
  const f16x8* BpU = (const f16x8*)fsTh + (((size_t)b << 12) + pup) * 16 + (lane >> 4);
  const f16x8* Ap  = (const f16x8*)WfB + lane;

#pragma unroll
  for (int q = 0; q < 8; ++q) {
    f16x8 bf = (q < 4) ? BpA[q * 4] : BpU[(q - 4) * 4];
#pragma unroll
    for (int m = 0; m < 8; ++m)
      acc[m] = __builtin_amdgcn_mfma_f32_16x16x32_f16(Ap[(q * 8 + m) * 64], bf, acc[m], 0, 0, 0);
  }

  const int r0 = (lane >> 4) * 4;
#pragma unroll
  for (int m = 0; m < 8; ++m) {
    f16x4 hh;
#pragma unroll
    for (int r = 0; r < 4; ++r) hh[r] = (_Float16)relu_(acc[m][r]);
    *(f16x4*)&offh[(((size_t)b << 14) + pxl) * 128 + m * 16 + r0] = hh;
  }
}

// ---------------------------------------------------------------------------
// com GEMM (LDS-staged, depth-2 B prefetch): om[b][oc][p], oc padded 256.
// ---------------------------------------------------------------------------
__global__ __launch_bounds__(256) void com_gemm_kernel(
    const _Float16* __restrict__ offh, const _Float16* __restrict__ WfP,
    const float* __restrict__ cb, float* __restrict__ om)
{
  const int b    = blockIdx.z;
  const int half = blockIdx.y;
  const int tid  = threadIdx.x;
  const int lane = tid & 63;
  const int px0  = blockIdx.x * 64 + (tid >> 6) * 16;
  const int pxl  = px0 + (lane & 15);
  const int h = pxl >> 7, w = pxl & 127;

  __shared__ f16x8 As[512];   // 8 KB

  f32x4 acc[8];
#pragma unroll
  for (int m = 0; m < 8; ++m) acc[m] = (f32x4){0.f, 0.f, 0.f, 0.f};

  const f16x8* Bbase = (const f16x8*)offh + ((size_t)b << 14) * 16 + (lane >> 4);
  const f16x8* Wp    = (const f16x8*)WfP + half * 512 + tid * 2;
  const f16x8 zero = {(_Float16)0.f, (_Float16)0.f, (_Float16)0.f, (_Float16)0.f,
                      (_Float16)0.f, (_Float16)0.f, (_Float16)0.f, (_Float16)0.f};

  auto loadB = [&](int t) -> f16x8 {
    const int kk = t >> 2, ic4 = t & 3;
    const int hh = h + kk / 3 - 1;
    const int ww = w + kk % 3 - 1;
    const bool valid = ((unsigned)hh < 128u) && ((unsigned)ww < 128u);
    const int ps = valid ? ((hh << 7) + ww) : 0;
    f16x8 bf = Bbase[(size_t)ps * 16 + ic4 * 4];
    return valid ? bf : zero;
  };

  f16x8 rA0 = Wp[0], rA1 = Wp[1];
  f16x8 bfA = loadB(0), bfB = loadB(1);

#pragma unroll 1
  for (int tt = 0; tt < 18; ++tt) {
    const int t0 = tt * 2;
    __syncthreads();
    As[tid * 2] = rA0; As[tid * 2 + 1] = rA1;
    __syncthreads();
    rA0 = Wp[(t0 + 1) * 1024]; rA1 = Wp[(t0 + 1) * 1024 + 1];
    {
      f16x8 bu = bfA;
      if (t0 + 2 < 36) bfA = loadB(t0 + 2);
#pragma unroll
      for (int m = 0; m < 8; ++m)
        acc[m] = __builtin_amdgcn_mfma_f32_16x16x32_f16(As[m * 64 + lane], bu, acc[m], 0, 0, 0);
    }
    __syncthreads();
    As[tid * 2] = rA0; As[tid * 2 + 1] = rA1;
    __syncthreads();
    if (t0 + 2 < 36) { rA0 = Wp[(t0 + 2) * 1024]; rA1 = Wp[(t0 + 2) * 1024 + 1]; }
    {
      f16x8 bu = bfB;
      if (t0 + 3 < 36) bfB = loadB(t0 + 3);
#pragma unroll
      for (int m = 0; m < 8; ++m)
        acc[m] = __builtin_amdgcn_mfma_f32_16x16x32_f16(As[m * 64 + lane], bu, acc[m], 0, 0, 0);
    }
  }

  const int r0i = (lane >> 4) * 4;
#pragma unroll
  for (int m = 0; m < 8; ++m) {
#pragma unroll
    for (int r = 0; r < 4; ++r) {
      int oc = half * 128 + m * 16 + r0i + r;
      if (oc < 216)
        om[((size_t)(b * 216 + oc) << 14) + pxl] = acc[m][r] + cb[oc];
    }
  }
}

// ---------------------------------------------------------------------------
// dcn SPLIT-K fused kernel: bilinear sample + einsum, K halves across blocks
// (grid y = kh in {0,1}, 18 chunks each -> 2x occupancy vs round-8 fused).
// Software pipeline: taps for chunk q+1 issued during bilinear+MFMA of q;
// om for q+2 in flight behind that. Writes f32 partials part[kh][b][px][64].
// Numerics: identical ops, f32 accumulation merely reassociated.
// ---------------------------------------------------------------------------
__global__ __launch_bounds__(256) void dcn_split_kernel(
    const _Float16* __restrict__ fsTh, const float* __restrict__ om,
    const _Float16* __restrict__ Wf2, float* __restrict__ part)
{
  const int b    = blockIdx.z;
  const int kh   = blockIdx.y;
  const int tid  = threadIdx.x;
  const int wv   = tid >> 6;
  const int lane = tid & 63;
  const int px0  = blockIdx.x * 64 + wv * 16;
  const int pxl  = px0 + (lane & 15);
  const int h = pxl >> 7, w = pxl & 127;
  const int t9add = lane >> 5;              // 0 or 1
  const int chalf = ((lane >> 4) & 1) << 3; // 0 or 8

  const float* omp = om + (((size_t)b * 216) << 14) + pxl;
  const _Float16* fb = fsTh + ((size_t)b << 19);
  const f16x8* Ap = (const f16x8*)Wf2 + lane;
  const int qbeg = kh * 18;

  f32x4 acc[4];
#pragma unroll
  for (int m = 0; m < 4; ++m) acc[m] = (f32x4){0.f, 0.f, 0.f, 0.f};

  auto loadOm = [&](int q, float& oy, float& ox, float& mr) {
    const int t9 = 2 * q + t9add;
    const int g = t9 / 9;
    const int k = t9 - g * 9;
    oy = omp[(size_t)(g * 18 + 2 * k) << 14];
    ox = omp[(size_t)(g * 18 + 2 * k + 1) << 14];
    mr = omp[(size_t)(144 + t9) << 14];
  };

  // prep: compute weights + issue 4 tap loads for chunk q from its om values
  auto prep = [&](int q, float oy, float ox, float mr,
                  float& w00, float& w01, float& w10, float& w11,
                  f16x8& t00, f16x8& t01, f16x8& t10, f16x8& t11) {
    const int t9 = 2 * q + t9add;
    const int g = t9 / 9;
    const int k = t9 - g * 9;
    const float mv = 1.f / (1.f + __expf(-mr));
    const float py  = (float)(h + k / 3 - 1) + oy;
    const float pxx = (float)(w + k % 3 - 1) + ox;
    const float y0f = floorf(py), x0f = floorf(pxx);
    const float ly = py - y0f, lx = pxx - x0f;
    const int y0 = (int)y0f, x0i = (int)x0f;
    const int y1 = y0 + 1, x1 = x0i + 1;
    const int y0c = min(max(y0, 0), 127), y1c = min(max(y1, 0), 127);
    const int x0c = min(max(x0i, 0), 127), x1c = min(max(x1, 0), 127);
    w00 = (1.f - ly) * (1.f - lx) * mv;
    w01 = (1.f - ly) * lx * mv;
    w10 = ly * (1.f - lx) * mv;
    w11 = ly * lx * mv;
    const bool vy0 = (unsigned)y0 < 128u, vy1 = (unsigned)y1 < 128u;
    const bool vx0 = (unsigned)x0i < 128u, vx1 = (unsigned)x1 < 128u;
    w00 = (vy0 && vx0) ? w00 : 0.f;
    w01 = (vy0 && vx1) ? w01 : 0.f;
    w10 = (vy1 && vx0) ? w10 : 0.f;
    w11 = (vy1 && vx1) ? w11 : 0.f;
    const int gb = g * 16 + chalf;
    const int a00 = ((((y0c >> 1) << 6) + (x0c >> 1)) << 7) + gb;
    const int a01 = ((((y0c >> 1) << 6) + (x1c >> 1)) << 7) + gb;
    const int a10 = ((((y1c >> 1) << 6) + (x0c >> 1)) << 7) + gb;
    const int a11 = ((((y1c >> 1) << 6) + (x1c >> 1)) << 7) + gb;
    t00 = *(const f16x8*)(fb + a00);
    t01 = *(const f16x8*)(fb + a01);
    t10 = *(const f16x8*)(fb + a10);
    t11 = *(const f16x8*)(fb + a11);
  };

  float oyB, oxB, mrB;
  float w00, w01, w10, w11;
  f16x8 t00, t01, t10, t11;
  {
    float oyA, oxA, mrA;
    loadOm(qbeg, oyA, oxA, mrA);
    loadOm(qbeg + 1, oyB, oxB, mrB);
    prep(qbeg, oyA, oxA, mrA, w00, w01, w10, w11, t00, t01, t10, t11);
  }

#pragma unroll 1
  for (int qq = 0; qq < 18; ++qq) {
    const int q = qbeg + qq;
    float nw00 = 0.f, nw01 = 0.f, nw10 = 0.f, nw11 = 0.f;
    f16x8 n00 = t00, n01 = t01, n10 = t10, n11 = t11;
    if (qq + 1 < 18) {
      prep(q + 1, oyB, oxB, mrB, nw00, nw01, nw10, nw11, n00, n01, n10, n11);
      if (qq + 2 < 18) loadOm(q + 2, oyB, oxB, mrB);
    }
    // consume current taps (compiler inserts waitcnt here, one chunk after issue)
    f16x8 bf;
#pragma unroll
    for (int j = 0; j < 8; ++j)
      bf[j] = (_Float16)(w00 * (float)t00[j] + w01 * (float)t01[j]
                       + w10 * (float)t10[j] + w11 * (float)t11[j]);
    const f16x8* ap = Ap + q * 256;
#pragma unroll
    for (int m = 0; m < 4; ++m)
      acc[m] = __builtin_amdgcn_mfma_f32_16x16x32_f16(ap[m * 64], bf, acc[m], 0, 0, 0);
    w00 = nw00; w01 = nw01; w10 = nw10; w11 = nw11;
    t00 = n00; t01 = n01; t10 = n10; t11 = n11;
  }

  const int r0 = (lane >> 4) * 4;
  float* pp = part + ((size_t)kh << 21) + ((((size_t)b << 14) + pxl) << 6);
#pragma unroll
  for (int m = 0; m < 4; ++m)
    *(f32x4*)(pp + m * 16 + r0) = acc[m];
}

// ---------------------------------------------------------------------------
// dcn reduce: alh[b][px][64] = f16(relu(part[0] + part[1] + db)).
// ---------------------------------------------------------------------------
__global__ __launch_bounds__(256) void dcn_reduce_kernel(
    const float* __restrict__ part, const float* __restrict__ db,
    _Float16* __restrict__ alh)
{
  const int idx = blockIdx.x * 256 + threadIdx.x;   // 2*16384*16 = 524,288
  const int oc4 = idx & 15;
  const size_t base = ((size_t)(idx >> 4) << 6) + oc4 * 4;  // (b*HW+px)*64 + oc
  f32x4 v0 = *(const f32x4*)(part + base);
  f32x4 v1 = *(const f32x4*)(part + ((size_t)1 << 21) + base);
  f16x4 hv;
#pragma unroll
  for (int r = 0; r < 4; ++r)
    hv[r] = (_Float16)relu_(v0[r] + v1[r] + db[oc4 * 4 + r]);
  *(f16x4*)&alh[base] = hv;
}

// ---------------------------------------------------------------------------
// cat GEMM: out[b][oc][p] = relu(cat_w @ feat_align) + arm. K=64 (2 chunks).
// ---------------------------------------------------------------------------
__global__ __launch_bounds__(256) void cat_gemm_kernel(
    const _Float16* __restrict__ alh, const _Float16* __restrict__ WfC,
    const float* __restrict__ arm, float* __restrict__ out)
{
  const int b    = blockIdx.y;
  const int tid  = threadIdx.x;
  const int wv   = tid >> 6;
  const int lane = tid & 63;
  const int px0  = blockIdx.x * 64 + wv * 16;
  const int pxl  = px0 + (lane & 15);

  f32x4 acc[8];
#pragma unroll
  for (int m = 0; m < 8; ++m) acc[m] = (f32x4){0.f, 0.f, 0.f, 0.f};

  const f16x8* Bp = (const f16x8*)alh + (((size_t)b << 14) + pxl) * 8 + (lane >> 4);
  const f16x8* Ap = (const f16x8*)WfC + lane;

#pragma unroll
  for (int q = 0; q < 2; ++q) {
    f16x8 bf = Bp[q * 4];
#pragma unroll
    for (int m = 0; m < 8; ++m)
      acc[m] = __builtin_amdgcn_mfma_f32_16x16x32_f16(Ap[(q * 8 + m) * 64], bf, acc[m], 0, 0, 0);
  }

  const int r0 = (lane >> 4) * 4;
#pragma unroll
  for (int m = 0; m < 8; ++m) {
#pragma unroll
    for (int r = 0; r < 4; ++r) {
      int oc = m * 16 + r0 + r;
      size_t a = ((size_t)(b * 128 + oc) << 14) + pxl;
      out[a] = relu_(acc[m][r]) + arm[a];
    }
  }
}

// ---------------------------------------------------------------------------
// FALLBACK path kernels (small ws): round-1 versions
// ---------------------------------------------------------------------------
__global__ __launch_bounds__(256) void com_conv_kernel(
    const float* __restrict__ x, const float* __restrict__ cw,
    const float* __restrict__ cb, float* __restrict__ om)
{
  const int b    = blockIdx.z;
  const int ocg  = blockIdx.y;
  const int tile = blockIdx.x;
  const int th = (tile >> 2) * 32, tw = (tile & 3) * 32;
  const int tid = threadIdx.x;
  const int lw = (tid & 7) * 4;
  const int lh = tid >> 3;

  __shared__ float Xs[8 * 34 * 34];

  float acc[8][4];
#pragma unroll
  for (int a = 0; a < 8; ++a)
#pragma unroll
    for (int p = 0; p < 4; ++p) acc[a][p] = 0.f;

  for (int cc = 0; cc < 128; cc += 8) {
    __syncthreads();
    for (int idx = tid; idx < 8 * 1156; idx += 256) {
      int ic  = idx / 1156;
      int rem = idx - ic * 1156;
      int yy  = rem / 34;
      int xx  = rem - yy * 34;
      int gh = th + yy - 1, gw = tw + xx - 1;
      float v = 0.f;
      if ((unsigned)gh < 128u && (unsigned)gw < 128u)
        v = x[((size_t)(b * 128 + cc + ic) << 14) + (gh << 7) + gw];
      Xs[idx] = v;
    }
    __syncthreads();
#pragma unroll 1
    for (int ic = 0; ic < 8; ++ic) {
      float xr[3][6];
#pragma unroll
      for (int ky = 0; ky < 3; ++ky)
#pragma unroll
        for (int xx = 0; xx < 6; ++xx)
          xr[ky][xx] = Xs[ic * 1156 + (lh + ky) * 34 + lw + xx];
      const float* wp = cw + ((size_t)(ocg * 8) * 128 + (cc + ic)) * 9;
#pragma unroll
      for (int a = 0; a < 8; ++a) {
        const float* w9 = wp + a * 1152;
#pragma unroll
        for (int ky = 0; ky < 3; ++ky)
#pragma unroll
          for (int kx = 0; kx < 3; ++kx) {
            float wv = w9[ky * 3 + kx];
#pragma unroll
            for (int p = 0; p < 4; ++p)
              acc[a][p] = fmaf(wv, xr[ky][kx + p], acc[a][p]);
          }
      }
    }
  }

#pragma unroll
  for (int a = 0; a < 8; ++a) {
    int oc = ocg * 8 + a;
    float bv = cb[oc];
    float4 r = make_float4(acc[a][0] + bv, acc[a][1] + bv,
                           acc[a][2] + bv, acc[a][3] + bv);
    *(float4*)(om + ((size_t)(b * 216 + oc) << 14) + ((th + lh) << 7) + tw + lw) = r;
  }
}

__global__ __launch_bounds__(256) void wt_kernel(const float* __restrict__ dw,
                                                 float* __restrict__ wT)
{
  int idx = blockIdx.x * 256 + threadIdx.x;
  int o    = idx & 63;
  int rest = idx >> 6;
  int k    = rest % 9;
  int gc   = rest / 9;
  wT[idx] = dw[(o * 128 + gc) * 9 + k];
}

__global__ __launch_bounds__(256) void dcn_kernel(
    const float* __restrict__ fs, const float* __restrict__ om,
    const float* __restrict__ wT, const float* __restrict__ db,
    float* __restrict__ al)
{
  const int b   = blockIdx.y;
  const int p0  = blockIdx.x * 32;
  const int tid = threadIdx.x;
  const int px  = tid & 31;
  const int g   = tid >> 5;
  const int p = p0 + px;
  const int h = p >> 7, w = p & 127;

  float acc[64];
#pragma unroll
  for (int o = 0; o < 64; ++o) acc[o] = 0.f;

  const size_t omb = ((size_t)b * 216) << 14;
  const float* fsg = fs + (((size_t)(b * 128 + g * 16)) << 12);
  const float* wg  = wT + g * (16 * 9 * 64);

#pragma unroll 1
  for (int k = 0; k < 9; ++k) {
    float offy = om[omb + ((size_t)(g * 18 + 2 * k) << 14) + p];
    float offx = om[omb + ((size_t)(g * 18 + 2 * k + 1) << 14) + p];
    float mraw = om[omb + ((size_t)(144 + g * 9 + k) << 14) + p];
    float mv = 1.f / (1.f + __expf(-mraw));

    float py  = (float)(h + k / 3 - 1) + offy;
    float pxx = (float)(w + k % 3 - 1) + offx;
    float y0f = floorf(py), x0f = floorf(pxx);
    float ly = py - y0f, lx = pxx - x0f;
    int y0 = (int)y0f, x0i = (int)x0f;
    int y1 = y0 + 1, x1 = x0i + 1;

    int y0c = min(max(y0, 0), 127), y1c = min(max(y1, 0), 127);
    int x0c = min(max(x0i, 0), 127), x1c = min(max(x1, 0), 127);
    int ry0 = (y0c >> 1) << 6, ry1 = (y1c >> 1) << 6;
    int cx0 = x0c >> 1, cx1 = x1c >> 1;

    float w00 = (1.f - ly) * (1.f - lx) * mv;
    float w01 = (1.f - ly) * lx * mv;
    float w10 = ly * (1.f - lx) * mv;
    float w11 = ly * lx * mv;
    bool vy0 = (unsigned)y0 < 128u, vy1 = (unsigned)y1 < 128u;
    bool vx0 = (unsigned)x0i < 128u, vx1 = (unsigned)x1 < 128u;
    w00 = (vy0 && vx0) ? w00 : 0.f;
    w01 = (vy0 && vx1) ? w01 : 0.f;
    w10 = (vy1 && vx0) ? w10 : 0.f;
    w11 = (vy1 && vx1) ? w11 : 0.f;

#pragma unroll 1
    for (int c = 0; c < 16; ++c) {
      const float* fc = fsg + (c << 12);
      float v00 = fc[ry0 + cx0];
      float v01 = fc[ry0 + cx1];
      float v10 = fc[ry1 + cx0];
      float v11 = fc[ry1 + cx1];
      float v = w00 * v00 + w01 * v01 + w10 * v10 + w11 * v11;
      const float* wp = wg + (c * 9 + k) * 64;
#pragma unroll
      for (int oq = 0; oq < 16; ++oq) {
        float4 w4 = *(const float4*)(wp + oq * 4);
        acc[oq * 4 + 0] = fmaf(v, w4.x, acc[oq * 4 + 0]);
        acc[oq * 4 + 1] = fmaf(v, w4.y, acc[oq * 4 + 1]);
        acc[oq * 4 + 2] = fmaf(v, w4.z, acc[oq * 4 + 2]);
        acc[oq * 4 + 3] = fmaf(v, w4.w, acc[oq * 4 + 3]);
      }
    }
  }

  __shared__ float red[256][17];
  const int px2 = tid & 31;
  const int og  = tid >> 5;
#pragma unroll
  for (int r = 0; r < 4; ++r) {
    __syncthreads();
#pragma unroll
    for (int j = 0; j < 16; ++j) red[tid][j] = acc[r * 16 + j];
    __syncthreads();
#pragma unroll
    for (int jj = 0; jj < 2; ++jj) {
      int ol = og * 2 + jj;
      float s = 0.f;
#pragma unroll
      for (int gg = 0; gg < 8; ++gg) s += red[gg * 32 + px2][ol];
      int oc = r * 16 + ol;
      s += db[oc];
      al[((size_t)(b * 64 + oc) << 14) + p0 + px2] = fmaxf(s, 0.f);
    }
  }
}

// ---------------------------------------------------------------------------
extern "C" void kernel_launch(void* const* d_in, const int* in_sizes, int n_in,
                              void* d_out, int out_size, void* d_ws, size_t ws_size,
                              hipStream_t stream)
{
  const float* feat_l   = (const float*)d_in[0];
  const float* feat_s   = (const float*)d_in[1];
  const float* fsm_w    = (const float*)d_in[2];
  const float* offset_w = (const float*)d_in[3];
  const float* com_w    = (const float*)d_in[4];
  const float* com_b    = (const float*)d_in[5];
  const float* dcn_w    = (const float*)d_in[6];
  const float* dcn_b    = (const float*)d_in[7];
  const float* cat_w    = (const float*)d_in[8];
  float* out = (float*)d_out;
  float* ws  = (float*)d_ws;

  const size_t NEED = (size_t)(4194304 + 7077888 + 2097152 + 1048576 + 37748736) * 4;

  if (ws_size >= NEED) {
    float* arm      = ws;                          // 4,194,304 f32
    float* om       = ws + 4194304;                // 7,077,888 f32
    _Float16* alh   = (_Float16*)(ws + 11272192);  // 2,097,152 f16
    _Float16* Wf2   = (_Float16*)(ws + 12320768);  // 73,728 f16
    _Float16* WfC   = (_Float16*)(ws + 12357632);  // 8,192 f16
    _Float16* fsTh  = (_Float16*)(ws + 13369344);  // 1,048,576 f16
    _Float16* flTh  = (_Float16*)(ws + 13893632);  // 4,194,304 f16
    _Float16* armh  = (_Float16*)(ws + 15990784);  // 4,194,304 f16
    _Float16* offh  = (_Float16*)(ws + 18087936);  // 4,194,304 f16
    float*    part  = ws + 20185088;               // 4,194,304 f32 (old valh slot)
    _Float16* WfA   = (_Float16*)(ws + 39059456);  // 16,384 f16
    _Float16* WfB   = (_Float16*)(ws + 39067648);  // 32,768 f16
    _Float16* WfP   = (_Float16*)(ws + 39084032);  // 294,912 f16

    hipLaunchKernelGGL(wfall_kernel, dim3(208), dim3(256), 0, stream,
                       fsm_w, offset_w, com_w, dcn_w, cat_w, WfA, WfB, WfP, Wf2, WfC);
    hipLaunchKernelGGL(t2h2_kernel, dim3(640, 4, 2), dim3(256), 0, stream,
                       feat_l, feat_s, flTh, fsTh);
    hipLaunchKernelGGL(fsm_gemm_kernel, dim3(256, 2), dim3(256), 0, stream,
                       flTh, WfA, arm, armh);
    hipLaunchKernelGGL(off_gemm_kernel, dim3(256, 2), dim3(256), 0, stream,
                       armh, fsTh, WfB, offh);
    hipLaunchKernelGGL(com_gemm_kernel, dim3(256, 2, 2), dim3(256), 0, stream,
                       offh, WfP, com_b, om);
    hipLaunchKernelGGL(dcn_split_kernel, dim3(256, 2, 2), dim3(256), 0, stream,
                       fsTh, om, Wf2, part);
    hipLaunchKernelGGL(dcn_reduce_kernel, dim3(2048), dim3(256), 0, stream,
                       part, dcn_b, alh);
    hipLaunchKernelGGL(cat_gemm_kernel, dim3(256, 2), dim3(256), 0, stream,
                       alh, WfC, arm, out);
  } else {
    float* arm = ws;
    float* off = ws + 4194304;
    float* om  = ws + 8388608;
    float* al  = ws + 15466496;
    float* wT  = ws + 17563648;

    hipLaunchKernelGGL(wt_kernel, dim3(288), dim3(256), 0, stream, dcn_w, wT);
    hipLaunchKernelGGL((conv1x1_kernel<0, 128>), dim3(256, 2), dim3(256), 0, stream,
                       feat_l, nullptr, fsm_w, arm);
    hipLaunchKernelGGL((conv1x1_kernel<1, 256>), dim3(256, 2), dim3(256), 0, stream,
                       arm, feat_s, offset_w, off);
    hipLaunchKernelGGL(com_conv_kernel, dim3(16, 27, 2), dim3(256), 0, stream,
                       off, com_w, com_b, om);
    hipLaunchKernelGGL(dcn_kernel, dim3(512, 2), dim3(256), 0, stream,
                       feat_s, om, wT, dcn_b, al);
    hipLaunchKernelGGL((conv1x1_kernel<2, 64>), dim3(256, 2), dim3(256), 0, stream,
                       al, arm, cat_w, out);
  }
}

// Round 10
// 186.619 us; speedup vs baseline: 1.0277x; 1.0277x over previous
//
#include <hip/hip_runtime.h>
#include <cstdint>
#include <cstddef>

// Problem constants
// B=2, C=128, H=W=128, Hs=Ws=64, DG=8, KK=9, CG=16, COUT_DCN=64, HW=16384

typedef _Float16 f16x8 __attribute__((ext_vector_type(8)));
typedef _Float16 f16x4 __attribute__((ext_vector_type(4)));
typedef float    f32x4 __attribute__((ext_vector_type(4)));

__device__ __forceinline__ float relu_(float x) { return fmaxf(x, 0.f); }

// ---------------------------------------------------------------------------
// conv1x1 (fp32, LDS-tiled) — FALLBACK path only.
// ---------------------------------------------------------------------------
template<int MODE, int CIN>
__global__ __launch_bounds__(256) void conv1x1_kernel(
    const float* __restrict__ in1, const float* __restrict__ in2,
    const float* __restrict__ Wm, float* __restrict__ out)
{
  constexpr int IN1C = (MODE == 2) ? 64 : 128;
  const int b  = blockIdx.y;
  const int p0 = blockIdx.x * 64;
  const int tid = threadIdx.x;
  const int tx = tid & 7;
  const int ty = tid >> 3;

  __shared__ float Xs[16][64];
  __shared__ float Wt[16][128];

  float acc[4][8];
#pragma unroll
  for (int i = 0; i < 4; ++i)
#pragma unroll
    for (int j = 0; j < 8; ++j) acc[i][j] = 0.f;

  const int cS  = tid >> 4;
  const int pxS = (tid & 15) * 4;
  const int ocS = (tid & 15) * 8;

  for (int cc = 0; cc < CIN; cc += 16) {
    __syncthreads();
    {
      int gc = cc + cS;
      float4 v;
      if (MODE == 1 && gc >= 128) {
        int sc = gc - 128;
        float t[4];
#pragma unroll
        for (int j = 0; j < 4; ++j) {
          int pp = p0 + pxS + j;
          int hh = pp >> 7, ww = pp & 127;
          t[j] = 2.f * in2[((size_t)(b * 128 + sc) << 12) + ((hh >> 1) << 6) + (ww >> 1)];
        }
        v = make_float4(t[0], t[1], t[2], t[3]);
      } else {
        v = *(const float4*)(in1 + ((size_t)(b * IN1C + gc) << 14) + p0 + pxS);
      }
      *(float4*)&Xs[cS][pxS] = v;
#pragma unroll
      for (int j = 0; j < 8; ++j)
        Wt[cS][ocS + j] = Wm[(ocS + j) * CIN + cc + cS];
    }
    __syncthreads();
#pragma unroll
    for (int c = 0; c < 16; ++c) {
      float4 wv = *(const float4*)&Wt[c][ty * 4];
      float4 x0 = *(const float4*)&Xs[c][tx * 8];
      float4 x1 = *(const float4*)&Xs[c][tx * 8 + 4];
      float xs[8] = {x0.x, x0.y, x0.z, x0.w, x1.x, x1.y, x1.z, x1.w};
      float wf[4] = {wv.x, wv.y, wv.z, wv.w};
#pragma unroll
      for (int i = 0; i < 4; ++i)
#pragma unroll
        for (int j = 0; j < 8; ++j)
          acc[i][j] = fmaf(wf[i], xs[j], acc[i][j]);
    }
  }

#pragma unroll
  for (int i = 0; i < 4; ++i) {
    int oc = ty * 4 + i;
    size_t base = ((size_t)(b * 128 + oc) << 14) + p0 + tx * 8;
    float r[8];
#pragma unroll
    for (int j = 0; j < 8; ++j) r[j] = relu_(acc[i][j]);
    if (MODE == 2) {
#pragma unroll
      for (int j = 0; j < 8; ++j) r[j] += in2[base + j];
    }
    *(float4*)(out + base)     = make_float4(r[0], r[1], r[2], r[3]);
    *(float4*)(out + base + 4) = make_float4(r[4], r[5], r[6], r[7]);
  }
}

// ---------------------------------------------------------------------------
// t2h2: fused transpose of feat_l and feat_s: [b][128][HW] f32 -> [b][HW][128] f16
// ---------------------------------------------------------------------------
__global__ __launch_bounds__(256) void t2h2_kernel(
    const float* __restrict__ fl, const float* __restrict__ fs,
    _Float16* __restrict__ flTh, _Float16* __restrict__ fsTh)
{
  const int bx = blockIdx.x;
  const float* src;
  _Float16* dst;
  int HW, p0;
  if (bx < 512) { src = fl; dst = flTh; HW = 16384; p0 = bx * 32; }
  else          { src = fs; dst = fsTh; HW = 4096;  p0 = (bx - 512) * 32; }
  const int b  = blockIdx.z;
  const int c0 = blockIdx.y * 32;
  const int tid = threadIdx.x;
  __shared__ float T[32][33];
  {
    int pxl = tid & 31, cy = tid >> 5;
#pragma unroll
    for (int j = 0; j < 4; ++j) {
      int c = cy + j * 8;
      T[c][pxl] = src[((size_t)(b * 128 + c0 + c)) * HW + p0 + pxl];
    }
  }
  __syncthreads();
  {
    int cq = tid & 7, pr = tid >> 3;
    f16x4 v;
#pragma unroll
    for (int e = 0; e < 4; ++e) v[e] = (_Float16)T[cq * 4 + e][pr];
    *(f16x4*)&dst[(((size_t)b * HW) + p0 + pr) * 128 + c0 + cq * 4] = v;
  }
}

// ---------------------------------------------------------------------------
// wfall: all 5 weight packs in one launch. Block ranges:
// [0,8) WfA | [8,24) WfB | [24,168) WfP | [168,204) Wf2 | [204,208) WfC
// ---------------------------------------------------------------------------
__global__ __launch_bounds__(256) void wfall_kernel(
    const float* __restrict__ fsm_w, const float* __restrict__ offset_w,
    const float* __restrict__ com_w, const float* __restrict__ dcn_w,
    const float* __restrict__ cat_w,
    _Float16* __restrict__ WfA, _Float16* __restrict__ WfB,
    _Float16* __restrict__ WfP, _Float16* __restrict__ Wf2,
    _Float16* __restrict__ WfC)
{
  const int bid = blockIdx.x;
  if (bid < 8) {                         // WfA: fsm_w [128][128]
    int idx = bid * 256 + threadIdx.x;
    int lane = idx & 63;
    int t = idx >> 6;
    int m = t & 7, q = t >> 3;
    int oc = m * 16 + (lane & 15);
    int c0 = q * 32 + (lane >> 4) * 8;
    f16x8 v;
#pragma unroll
    for (int j = 0; j < 8; ++j) v[j] = (_Float16)fsm_w[oc * 128 + c0 + j];
    ((f16x8*)WfA)[idx] = v;
  } else if (bid < 24) {                 // WfB: offset_w [128][256], x2 on c>=128
    int idx = (bid - 8) * 256 + threadIdx.x;
    int lane = idx & 63;
    int t = idx >> 6;
    int m = t & 7, q = t >> 3;
    int oc = m * 16 + (lane & 15);
    int c0 = q * 32 + (lane >> 4) * 8;
    float s = (q >= 4) ? 2.f : 1.f;
    f16x8 v;
#pragma unroll
    for (int j = 0; j < 8; ++j) v[j] = (_Float16)(offset_w[oc * 256 + c0 + j] * s);
    ((f16x8*)WfB)[idx] = v;
  } else if (bid < 168) {                // WfP: com_w, oc-half-major, pad 256
    int idx = (bid - 24) * 256 + threadIdx.x;
    int lane = idx & 63;
    int t = idx >> 6;
    int m = t & 7;
    int t2 = t >> 3;
    int half = t2 & 1, q = t2 >> 1;
    int kk = q >> 2;
    int ic0 = (q & 3) * 32 + (lane >> 4) * 8;
    int oc = half * 128 + m * 16 + (lane & 15);
    f16x8 v;
#pragma unroll
    for (int j = 0; j < 8; ++j) {
      float x = (oc < 216) ? com_w[((size_t)oc * 128 + ic0 + j) * 9 + kk] : 0.f;
      v[j] = (_Float16)x;
    }
    ((f16x8*)WfP)[idx] = v;
  } else if (bid < 204) {                // Wf2: dcn_w, r' = (g*9+k)*16+c
    int idx = (bid - 168) * 256 + threadIdx.x;
    int lane = idx & 63;
    int t = idx >> 6;
    int m = t & 3, q = t >> 2;
    int oc = m * 16 + (lane & 15);
    f16x8 v;
#pragma unroll
    for (int j = 0; j < 8; ++j) {
      int rp = q * 32 + (lane >> 4) * 8 + j;
      int c = rp & 15, tt = rp >> 4;
      int g = tt / 9, k = tt % 9;
      v[j] = (_Float16)dcn_w[((size_t)oc * 128 + g * 16 + c) * 9 + k];
    }
    ((f16x8*)Wf2)[idx] = v;
  } else {                               // WfC: cat_w [128][64]
    int idx = (bid - 204) * 256 + threadIdx.x;
    int lane = idx & 63;
    int t = idx >> 6;
    int m = t & 7, q = t >> 3;
    int oc = m * 16 + (lane & 15);
    int k0 = q * 32 + (lane >> 4) * 8;
    f16x8 v;
#pragma unroll
    for (int j = 0; j < 8; ++j) v[j] = (_Float16)cat_w[oc * 64 + k0 + j];
    ((f16x8*)WfC)[idx] = v;
  }
}

// ---------------------------------------------------------------------------
// fsm GEMM: arm = relu(fsm_w @ feat_l). Outputs arm f32 [oc][p] + armh f16 [p][oc].
// ---------------------------------------------------------------------------
__global__ __launch_bounds__(256) void fsm_gemm_kernel(
    const _Float16* __restrict__ flTh, const _Float16* __restrict__ WfA,
    float* __restrict__ arm, _Float16* __restrict__ armh)
{
  const int b    = blockIdx.y;
  const int tid  = threadIdx.x;
  const int wv   = tid >> 6;
  const int lane = tid & 63;
  const int px0  = blockIdx.x * 64 + wv * 16;
  const int pxl  = px0 + (lane & 15);

  f32x4 acc[8];
#pragma unroll
  for (int m = 0; m < 8; ++m) acc[m] = (f32x4){0.f, 0.f, 0.f, 0.f};

  const f16x8* Bp = (const f16x8*)flTh + (((size_t)b << 14) + pxl) * 16 + (lane >> 4);
  const f16x8* Ap = (const f16x8*)WfA + lane;

#pragma unroll
  for (int q = 0; q < 4; ++q) {
    f16x8 bf = Bp[q * 4];
#pragma unroll
    for (int m = 0; m < 8; ++m)
      acc[m] = __builtin_amdgcn_mfma_f32_16x16x32_f16(Ap[(q * 8 + m) * 64], bf, acc[m], 0, 0, 0);
  }

  const int r0 = (lane >> 4) * 4;
#pragma unroll
  for (int m = 0; m < 8; ++m) {
    f16x4 h;
#pragma unroll
    for (int r = 0; r < 4; ++r) {
      float v = relu_(acc[m][r]);
      arm[((size_t)(b * 128 + m * 16 + r0 + r) << 14) + pxl] = v;
      h[r] = (_Float16)v;
    }
    *(f16x4*)&armh[(((size_t)b << 14) + pxl) * 128 + m * 16 + r0] = h;
  }
}

// ---------------------------------------------------------------------------
// offset GEMM: offh = relu(offset_w @ [armh ; 2*featup]) in f16 [p][128].
// ---------------------------------------------------------------------------
__global__ __launch_bounds__(256) void off_gemm_kernel(
    const _Float16* __restrict__ armh, const _Float16* __restrict__ fsTh,
    const _Float16* __restrict__ WfB, _Float16* __restrict__ offh)
{
  const int b    = blockIdx.y;
  const int tid  = threadIdx.x;
  const int wv   = tid >> 6;
  const int lane = tid & 63;
  const int px0  = blockIdx.x * 64 + wv * 16;
  const int pxl  = px0 + (lane & 15);
  const int h = pxl >> 7, w = pxl & 127;
  const int pup = ((h >> 1) << 6) + (w >> 1);

  f32x4 acc[8];
#pragma unroll
  for (int m = 0; m < 8; ++m) acc[m] = (f32x4){0.f, 0.f, 0.f, 0.f};

  const f16x8* BpA = (const f16x8*)armh + (((size_t)b << 14) + pxl) * 16 + (lane >> 4);
  const f16x8* BpU = (const f16x8*)fsTh + (((size_t)b << 12) + pup) * 16 + (lane >> 4);
  const f16x8* Ap  = (const f16x8*)WfB + lane;

#pragma unroll
  for (int q = 0; q < 8; ++q) {
    f16x8 bf = (q < 4) ? BpA[q * 4] : BpU[(q - 4) * 4];
#pragma unroll
    for (int m = 0; m < 8; ++m)
      acc[m] = __builtin_amdgcn_mfma_f32_16x16x32_f16(Ap[(q * 8 + m) * 64], bf, acc[m], 0, 0, 0);
  }

  const int r0 = (lane >> 4) * 4;
#pragma unroll
  for (int m = 0; m < 8; ++m) {
    f16x4 hh;
#pragma unroll
    for (int r = 0; r < 4; ++r) hh[r] = (_Float16)relu_(acc[m][r]);
    *(f16x4*)&offh[(((size_t)b << 14) + pxl) * 128 + m * 16 + r0] = hh;
  }
}

// ---------------------------------------------------------------------------
// com GEMM (LDS-staged, depth-2 B prefetch): omh f16 [b][oc][p], oc padded 256.
// ---------------------------------------------------------------------------
__global__ __launch_bounds__(256) void com_gemm_kernel(
    const _Float16* __restrict__ offh, const _Float16* __restrict__ WfP,
    const float* __restrict__ cb, _Float16* __restrict__ omh)
{
  const int b    = blockIdx.z;
  const int half = blockIdx.y;
  const int tid  = threadIdx.x;
  const int lane = tid & 63;
  const int px0  = blockIdx.x * 64 + (tid >> 6) * 16;
  const int pxl  = px0 + (lane & 15);
  const int h = pxl >> 7, w = pxl & 127;

  __shared__ f16x8 As[512];   // 8 KB

  f32x4 acc[8];
#pragma unroll
  for (int m = 0; m < 8; ++m) acc[m] = (f32x4){0.f, 0.f, 0.f, 0.f};

  const f16x8* Bbase = (const f16x8*)offh + ((size_t)b << 14) * 16 + (lane >> 4);
  const f16x8* Wp    = (const f16x8*)WfP + half * 512 + tid * 2;
  const f16x8 zero = {(_Float16)0.f, (_Float16)0.f, (_Float16)0.f, (_Float16)0.f,
                      (_Float16)0.f, (_Float16)0.f, (_Float16)0.f, (_Float16)0.f};

  auto loadB = [&](int t) -> f16x8 {
    const int kk = t >> 2, ic4 = t & 3;
    const int hh = h + kk / 3 - 1;
    const int ww = w + kk % 3 - 1;
    const bool valid = ((unsigned)hh < 128u) && ((unsigned)ww < 128u);
    const int ps = valid ? ((hh << 7) + ww) : 0;
    f16x8 bf = Bbase[(size_t)ps * 16 + ic4 * 4];
    return valid ? bf : zero;
  };

  f16x8 rA0 = Wp[0], rA1 = Wp[1];
  f16x8 bfA = loadB(0), bfB = loadB(1);

#pragma unroll 1
  for (int tt = 0; tt < 18; ++tt) {
    const int t0 = tt * 2;
    __syncthreads();
    As[tid * 2] = rA0; As[tid * 2 + 1] = rA1;
    __syncthreads();
    rA0 = Wp[(t0 + 1) * 1024]; rA1 = Wp[(t0 + 1) * 1024 + 1];
    {
      f16x8 bu = bfA;
      if (t0 + 2 < 36) bfA = loadB(t0 + 2);
#pragma unroll
      for (int m = 0; m < 8; ++m)
        acc[m] = __builtin_amdgcn_mfma_f32_16x16x32_f16(As[m * 64 + lane], bu, acc[m], 0, 0, 0);
    }
    __syncthreads();
    As[tid * 2] = rA0; As[tid * 2 + 1] = rA1;
    __syncthreads();
    if (t0 + 2 < 36) { rA0 = Wp[(t0 + 2) * 1024]; rA1 = Wp[(t0 + 2) * 1024 + 1]; }
    {
      f16x8 bu = bfB;
      if (t0 + 3 < 36) bfB = loadB(t0 + 3);
#pragma unroll
      for (int m = 0; m < 8; ++m)
        acc[m] = __builtin_amdgcn_mfma_f32_16x16x32_f16(As[m * 64 + lane], bu, acc[m], 0, 0, 0);
    }
  }

  const int r0i = (lane >> 4) * 4;
#pragma unroll
  for (int m = 0; m < 8; ++m) {
#pragma unroll
    for (int r = 0; r < 4; ++r) {
      int oc = half * 128 + m * 16 + r0i + r;
      if (oc < 216)
        omh[((size_t)(b * 216 + oc) << 14) + pxl] = (_Float16)(acc[m][r] + cb[oc]);
    }
  }
}

// ---------------------------------------------------------------------------
// dcn FUSED kernel (round-8 structure, omh f16): bilinear sampling + masked
// einsum in one pass. Wave = 16 px x 64 oc, K = 1152 in 36 chunks.
// Per chunk, lane s=lane>>4 supplies B-fragment elements for
// t9 = 2q + (lane>>5), c = ((lane>>4)&1)*8 + j computed IN-REGISTER.
// omh is L2-resident f16 (14 MB). Writes alh f16 [b][p][64].
// ---------------------------------------------------------------------------
__global__ __launch_bounds__(256) void dcn_fused_kernel(
    const _Float16* __restrict__ fsTh, const _Float16* __restrict__ omh,
    const _Float16* __restrict__ Wf2, const float* __restrict__ db,
    _Float16* __restrict__ alh)
{
  const int b    = blockIdx.y;
  const int tid  = threadIdx.x;
  const int wv   = tid >> 6;
  const int lane = tid & 63;
  const int px0  = blockIdx.x * 64 + wv * 16;
  const int pxl  = px0 + (lane & 15);
  const int h = pxl >> 7, w = pxl & 127;
  const int t9add = lane >> 5;             // 0 or 1
  const int chalf = ((lane >> 4) & 1) << 3; // 0 or 8

  const _Float16* omp = omh + (((size_t)b * 216) << 14) + pxl;
  const _Float16* fb = fsTh + ((size_t)b << 19);
  const f16x8* Ap = (const f16x8*)Wf2 + lane;

  f32x4 acc[4];
#pragma unroll
  for (int m = 0; m < 4; ++m) acc[m] = (f32x4){0.f, 0.f, 0.f, 0.f};

#pragma unroll 1
  for (int q = 0; q < 36; ++q) {
    const int t9 = 2 * q + t9add;
    const int g = t9 / 9;
    const int k = t9 - g * 9;

    const float offy = (float)omp[(size_t)(g * 18 + 2 * k) << 14];
    const float offx = (float)omp[(size_t)(g * 18 + 2 * k + 1) << 14];
    const float mraw = (float)omp[(size_t)(144 + t9) << 14];
    const float mv = 1.f / (1.f + __expf(-mraw));

    const float py  = (float)(h + k / 3 - 1) + offy;
    const float pxx = (float)(w + k % 3 - 1) + offx;
    const float y0f = floorf(py), x0f = floorf(pxx);
    const float ly = py - y0f, lx = pxx - x0f;
    const int y0 = (int)y0f, x0i = (int)x0f;
    const int y1 = y0 + 1, x1 = x0i + 1;

    const int y0c = min(max(y0, 0), 127), y1c = min(max(y1, 0), 127);
    const int x0c = min(max(x0i, 0), 127), x1c = min(max(x1, 0), 127);

    float w00 = (1.f - ly) * (1.f - lx) * mv;
    float w01 = (1.f - ly) * lx * mv;
    float w10 = ly * (1.f - lx) * mv;
    float w11 = ly * lx * mv;
    const bool vy0 = (unsigned)y0 < 128u, vy1 = (unsigned)y1 < 128u;
    const bool vx0 = (unsigned)x0i < 128u, vx1 = (unsigned)x1 < 128u;
    w00 = (vy0 && vx0) ? w00 : 0.f;
    w01 = (vy0 && vx1) ? w01 : 0.f;
    w10 = (vy1 && vx0) ? w10 : 0.f;
    w11 = (vy1 && vx1) ? w11 : 0.f;

    const int gb = g * 16 + chalf;
    const int a00 = ((((y0c >> 1) << 6) + (x0c >> 1)) << 7) + gb;
    const int a01 = ((((y0c >> 1) << 6) + (x1c >> 1)) << 7) + gb;
    const int a10 = ((((y1c >> 1) << 6) + (x0c >> 1)) << 7) + gb;
    const int a11 = ((((y1c >> 1) << 6) + (x1c >> 1)) << 7) + gb;

    f16x8 t00 = *(const f16x8*)(fb + a00);
    f16x8 t01 = *(const f16x8*)(fb + a01);
    f16x8 t10 = *(const f16x8*)(fb + a10);
    f16x8 t11 = *(const f16x8*)(fb + a11);

    f16x8 bf;
#pragma unroll
    for (int j = 0; j < 8; ++j)
      bf[j] = (_Float16)(w00 * (float)t00[j] + w01 * (float)t01[j]
                       + w10 * (float)t10[j] + w11 * (float)t11[j]);

    const f16x8* ap = Ap + q * 256;
#pragma unroll
    for (int m = 0; m < 4; ++m)
      acc[m] = __builtin_amdgcn_mfma_f32_16x16x32_f16(ap[m * 64], bf, acc[m], 0, 0, 0);
  }

  const int r0 = (lane >> 4) * 4;
#pragma unroll
  for (int m = 0; m < 4; ++m) {
    f16x4 hv;
#pragma unroll
    for (int r = 0; r < 4; ++r) {
      int oc = m * 16 + r0 + r;
      hv[r] = (_Float16)relu_(acc[m][r] + db[oc]);
    }
    *(f16x4*)&alh[(((size_t)b << 14) + pxl) * 64 + m * 16 + r0] = hv;
  }
}

// ---------------------------------------------------------------------------
// cat GEMM: out[b][oc][p] = relu(cat_w @ feat_align) + arm. K=64 (2 chunks).
// ---------------------------------------------------------------------------
__global__ __launch_bounds__(256) void cat_gemm_kernel(
    const _Float16* __restrict__ alh, const _Float16* __restrict__ WfC,
    const float* __restrict__ arm, float* __restrict__ out)
{
  const int b    = blockIdx.y;
  const int tid  = threadIdx.x;
  const int wv   = tid >> 6;
  const int lane = tid & 63;
  const int px0  = blockIdx.x * 64 + wv * 16;
  const int pxl  = px0 + (lane & 15);

  f32x4 acc[8];
#pragma unroll
  for (int m = 0; m < 8; ++m) acc[m] = (f32x4){0.f, 0.f, 0.f, 0.f};

  const f16x8* Bp = (const f16x8*)alh + (((size_t)b << 14) + pxl) * 8 + (lane >> 4);
  const f16x8* Ap = (const f16x8*)WfC + lane;

#pragma unroll
  for (int q = 0; q < 2; ++q) {
    f16x8 bf = Bp[q * 4];
#pragma unroll
    for (int m = 0; m < 8; ++m)
      acc[m] = __builtin_amdgcn_mfma_f32_16x16x32_f16(Ap[(q * 8 + m) * 64], bf, acc[m], 0, 0, 0);
  }

  const int r0 = (lane >> 4) * 4;
#pragma unroll
  for (int m = 0; m < 8; ++m) {
#pragma unroll
    for (int r = 0; r < 4; ++r) {
      int oc = m * 16 + r0 + r;
      size_t a = ((size_t)(b * 128 + oc) << 14) + pxl;
      out[a] = relu_(acc[m][r]) + arm[a];
    }
  }
}

// ---------------------------------------------------------------------------
// FALLBACK path kernels (small ws): round-1 versions
// ---------------------------------------------------------------------------
__global__ __launch_bounds__(256) void com_conv_kernel(
    const float* __restrict__ x, const float* __restrict__ cw,
    const float* __restrict__ cb, float* __restrict__ om)
{
  const int b    = blockIdx.z;
  const int ocg  = blockIdx.y;
  const int tile = blockIdx.x;
  const int th = (tile >> 2) * 32, tw = (tile & 3) * 32;
  const int tid = threadIdx.x;
  const int lw = (tid & 7) * 4;
  const int lh = tid >> 3;

  __shared__ float Xs[8 * 34 * 34];

  float acc[8][4];
#pragma unroll
  for (int a = 0; a < 8; ++a)
#pragma unroll
    for (int p = 0; p < 4; ++p) acc[a][p] = 0.f;

  for (int cc = 0; cc < 128; cc += 8) {
    __syncthreads();
    for (int idx = tid; idx < 8 * 1156; idx += 256) {
      int ic  = idx / 1156;
      int rem = idx - ic * 1156;
      int yy  = rem / 34;
      int xx  = rem - yy * 34;
      int gh = th + yy - 1, gw = tw + xx - 1;
      float v = 0.f;
      if ((unsigned)gh < 128u && (unsigned)gw < 128u)
        v = x[((size_t)(b * 128 + cc + ic) << 14) + (gh << 7) + gw];
      Xs[idx] = v;
    }
    __syncthreads();
#pragma unroll 1
    for (int ic = 0; ic < 8; ++ic) {
      float xr[3][6];
#pragma unroll
      for (int ky = 0; ky < 3; ++ky)
#pragma unroll
        for (int xx = 0; xx < 6; ++xx)
          xr[ky][xx] = Xs[ic * 1156 + (lh + ky) * 34 + lw + xx];
      const float* wp = cw + ((size_t)(ocg * 8) * 128 + (cc + ic)) * 9;
#pragma unroll
      for (int a = 0; a < 8; ++a) {
        const float* w9 = wp + a * 1152;
#pragma unroll
        for (int ky = 0; ky < 3; ++ky)
#pragma unroll
          for (int kx = 0; kx < 3; ++kx) {
            float wv = w9[ky * 3 + kx];
#pragma unroll
            for (int p = 0; p < 4; ++p)
              acc[a][p] = fmaf(wv, xr[ky][kx + p], acc[a][p]);
          }
      }
    }
  }

#pragma unroll
  for (int a = 0; a < 8; ++a) {
    int oc = ocg * 8 + a;
    float bv = cb[oc];
    float4 r = make_float4(acc[a][0] + bv, acc[a][1] + bv,
                           acc[a][2] + bv, acc[a][3] + bv);
    *(float4*)(om + ((size_t)(b * 216 + oc) << 14) + ((th + lh) << 7) + tw + lw) = r;
  }
}

__global__ __launch_bounds__(256) void wt_kernel(const float* __restrict__ dw,
                                                 float* __restrict__ wT)
{
  int idx = blockIdx.x * 256 + threadIdx.x;
  int o    = idx & 63;
  int rest = idx >> 6;
  int k    = rest % 9;
  int gc   = rest / 9;
  wT[idx] = dw[(o * 128 + gc) * 9 + k];
}

__global__ __launch_bounds__(256) void dcn_kernel(
    const float* __restrict__ fs, const float* __restrict__ om,
    const float* __restrict__ wT, const float* __restrict__ db,
    float* __restrict__ al)
{
  const int b   = blockIdx.y;
  const int p0  = blockIdx.x * 32;
  const int tid = threadIdx.x;
  const int px  = tid & 31;
  const int g   = tid >> 5;
  const int p = p0 + px;
  const int h = p >> 7, w = p & 127;

  float acc[64];
#pragma unroll
  for (int o = 0; o < 64; ++o) acc[o] = 0.f;

  const size_t omb = ((size_t)b * 216) << 14;
  const float* fsg = fs + (((size_t)(b * 128 + g * 16)) << 12);
  const float* wg  = wT + g * (16 * 9 * 64);

#pragma unroll 1
  for (int k = 0; k < 9; ++k) {
    float offy = om[omb + ((size_t)(g * 18 + 2 * k) << 14) + p];
    float offx = om[omb + ((size_t)(g * 18 + 2 * k + 1) << 14) + p];
    float mraw = om[omb + ((size_t)(144 + g * 9 + k) << 14) + p];
    float mv = 1.f / (1.f + __expf(-mraw));

    float py  = (float)(h + k / 3 - 1) + offy;
    float pxx = (float)(w + k % 3 - 1) + offx;
    float y0f = floorf(py), x0f = floorf(pxx);
    float ly = py - y0f, lx = pxx - x0f;
    int y0 = (int)y0f, x0i = (int)x0f;
    int y1 = y0 + 1, x1 = x0i + 1;

    int y0c = min(max(y0, 0), 127), y1c = min(max(y1, 0), 127);
    int x0c = min(max(x0i, 0), 127), x1c = min(max(x1, 0), 127);
    int ry0 = (y0c >> 1) << 6, ry1 = (y1c >> 1) << 6;
    int cx0 = x0c >> 1, cx1 = x1c >> 1;

    float w00 = (1.f - ly) * (1.f - lx) * mv;
    float w01 = (1.f - ly) * lx * mv;
    float w10 = ly * (1.f - lx) * mv;
    float w11 = ly * lx * mv;
    bool vy0 = (unsigned)y0 < 128u, vy1 = (unsigned)y1 < 128u;
    bool vx0 = (unsigned)x0i < 128u, vx1 = (unsigned)x1 < 128u;
    w00 = (vy0 && vx0) ? w00 : 0.f;
    w01 = (vy0 && vx1) ? w01 : 0.f;
    w10 = (vy1 && vx0) ? w10 : 0.f;
    w11 = (vy1 && vx1) ? w11 : 0.f;

#pragma unroll 1
    for (int c = 0; c < 16; ++c) {
      const float* fc = fsg + (c << 12);
      float v00 = fc[ry0 + cx0];
      float v01 = fc[ry0 + cx1];
      float v10 = fc[ry1 + cx0];
      float v11 = fc[ry1 + cx1];
      float v = w00 * v00 + w01 * v01 + w10 * v10 + w11 * v11;
      const float* wp = wg + (c * 9 + k) * 64;
#pragma unroll
      for (int oq = 0; oq < 16; ++oq) {
        float4 w4 = *(const float4*)(wp + oq * 4);
        acc[oq * 4 + 0] = fmaf(v, w4.x, acc[oq * 4 + 0]);
        acc[oq * 4 + 1] = fmaf(v, w4.y, acc[oq * 4 + 1]);
        acc[oq * 4 + 2] = fmaf(v, w4.z, acc[oq * 4 + 2]);
        acc[oq * 4 + 3] = fmaf(v, w4.w, acc[oq * 4 + 3]);
      }
    }
  }

  __shared__ float red[256][17];
  const int px2 = tid & 31;
  const int og  = tid >> 5;
#pragma unroll
  for (int r = 0; r < 4; ++r) {
    __syncthreads();
#pragma unroll
    for (int j = 0; j < 16; ++j) red[tid][j] = acc[r * 16 + j];
    __syncthreads();
#pragma unroll
    for (int jj = 0; jj < 2; ++jj) {
      int ol = og * 2 + jj;
      float s = 0.f;
#pragma unroll
      for (int gg = 0; gg < 8; ++gg) s += red[gg * 32 + px2][ol];
      int oc = r * 16 + ol;
      s += db[oc];
      al[((size_t)(b * 64 + oc) << 14) + p0 + px2] = fmaxf(s, 0.f);
    }
  }
}

// ---------------------------------------------------------------------------
extern "C" void kernel_launch(void* const* d_in, const int* in_sizes, int n_in,
                              void* d_out, int out_size, void* d_ws, size_t ws_size,
                              hipStream_t stream)
{
  const float* feat_l   = (const float*)d_in[0];
  const float* feat_s   = (const float*)d_in[1];
  const float* fsm_w    = (const float*)d_in[2];
  const float* offset_w = (const float*)d_in[3];
  const float* com_w    = (const float*)d_in[4];
  const float* com_b    = (const float*)d_in[5];
  const float* dcn_w    = (const float*)d_in[6];
  const float* dcn_b    = (const float*)d_in[7];
  const float* cat_w    = (const float*)d_in[8];
  float* out = (float*)d_out;
  float* ws  = (float*)d_ws;

  const size_t NEED = (size_t)(4194304 + 7077888 + 2097152 + 1048576 + 37748736) * 4;

  if (ws_size >= NEED) {
    float* arm      = ws;                          // 4,194,304 f32
    _Float16* omh   = (_Float16*)(ws + 4194304);   // 7,077,888 f16 (in old om slot)
    _Float16* alh   = (_Float16*)(ws + 11272192);  // 2,097,152 f16
    _Float16* Wf2   = (_Float16*)(ws + 12320768);  // 73,728 f16
    _Float16* WfC   = (_Float16*)(ws + 12357632);  // 8,192 f16
    _Float16* fsTh  = (_Float16*)(ws + 13369344);  // 1,048,576 f16
    _Float16* flTh  = (_Float16*)(ws + 13893632);  // 4,194,304 f16
    _Float16* armh  = (_Float16*)(ws + 15990784);  // 4,194,304 f16
    _Float16* offh  = (_Float16*)(ws + 18087936);  // 4,194,304 f16
    _Float16* WfA   = (_Float16*)(ws + 39059456);  // 16,384 f16
    _Float16* WfB   = (_Float16*)(ws + 39067648);  // 32,768 f16
    _Float16* WfP   = (_Float16*)(ws + 39084032);  // 294,912 f16

    hipLaunchKernelGGL(wfall_kernel, dim3(208), dim3(256), 0, stream,
                       fsm_w, offset_w, com_w, dcn_w, cat_w, WfA, WfB, WfP, Wf2, WfC);
    hipLaunchKernelGGL(t2h2_kernel, dim3(640, 4, 2), dim3(256), 0, stream,
                       feat_l, feat_s, flTh, fsTh);
    hipLaunchKernelGGL(fsm_gemm_kernel, dim3(256, 2), dim3(256), 0, stream,
                       flTh, WfA, arm, armh);
    hipLaunchKernelGGL(off_gemm_kernel, dim3(256, 2), dim3(256), 0, stream,
                       armh, fsTh, WfB, offh);
    hipLaunchKernelGGL(com_gemm_kernel, dim3(256, 2, 2), dim3(256), 0, stream,
                       offh, WfP, com_b, omh);
    hipLaunchKernelGGL(dcn_fused_kernel, dim3(256, 2), dim3(256), 0, stream,
                       fsTh, omh, Wf2, dcn_b, alh);
    hipLaunchKernelGGL(cat_gemm_kernel, dim3(256, 2), dim3(256), 0, stream,
                       alh, WfC, arm, out);
  } else {
    float* arm = ws;
    float* off = ws + 4194304;
    float* om  = ws + 8388608;
    float* al  = ws + 15466496;
    float* wT  = ws + 17563648;

    hipLaunchKernelGGL(wt_kernel, dim3(288), dim3(256), 0, stream, dcn_w, wT);
    hipLaunchKernelGGL((conv1x1_kernel<0, 128>), dim3(256, 2), dim3(256), 0, stream,
                       feat_l, nullptr, fsm_w, arm);
    hipLaunchKernelGGL((conv1x1_kernel<1, 256>), dim3(256, 2), dim3(256), 0, stream,
                       arm, feat_s, offset_w, off);
    hipLaunchKernelGGL(com_conv_kernel, dim3(16, 27, 2), dim3(256), 0, stream,
                       off, com_w, com_b, om);
    hipLaunchKernelGGL(dcn_kernel, dim3(512, 2), dim3(256), 0, stream,
                       feat_s, om, wT, dcn_b, al);
    hipLaunchKernelGGL((conv1x1_kernel<2, 64>), dim3(256, 2), dim3(256), 0, stream,
                       al, arm, cat_w, out);
  }
}

// Round 11
// 186.325 us; speedup vs baseline: 1.0293x; 1.0016x over previous
//
#include <hip/hip_runtime.h>
#include <cstdint>
#include <cstddef>

// Problem constants
// B=2, C=128, H=W=128, Hs=Ws=64, DG=8, KK=9, CG=16, COUT_DCN=64, HW=16384

typedef _Float16 f16x8 __attribute__((ext_vector_type(8)));
typedef _Float16 f16x4 __attribute__((ext_vector_type(4)));
typedef float    f32x4 __attribute__((ext_vector_type(4)));

__device__ __forceinline__ float relu_(float x) { return fmaxf(x, 0.f); }

// ---------------------------------------------------------------------------
// conv1x1 (fp32, LDS-tiled) — FALLBACK path only.
// ---------------------------------------------------------------------------
template<int MODE, int CIN>
__global__ __launch_bounds__(256) void conv1x1_kernel(
    const float* __restrict__ in1, const float* __restrict__ in2,
    const float* __restrict__ Wm, float* __restrict__ out)
{
  constexpr int IN1C = (MODE == 2) ? 64 : 128;
  const int b  = blockIdx.y;
  const int p0 = blockIdx.x * 64;
  const int tid = threadIdx.x;
  const int tx = tid & 7;
  const int ty = tid >> 3;

  __shared__ float Xs[16][64];
  __shared__ float Wt[16][128];

  float acc[4][8];
#pragma unroll
  for (int i = 0; i < 4; ++i)
#pragma unroll
    for (int j = 0; j < 8; ++j) acc[i][j] = 0.f;

  const int cS  = tid >> 4;
  const int pxS = (tid & 15) * 4;
  const int ocS = (tid & 15) * 8;

  for (int cc = 0; cc < CIN; cc += 16) {
    __syncthreads();
    {
      int gc = cc + cS;
      float4 v;
      if (MODE == 1 && gc >= 128) {
        int sc = gc - 128;
        float t[4];
#pragma unroll
        for (int j = 0; j < 4; ++j) {
          int pp = p0 + pxS + j;
          int hh = pp >> 7, ww = pp & 127;
          t[j] = 2.f * in2[((size_t)(b * 128 + sc) << 12) + ((hh >> 1) << 6) + (ww >> 1)];
        }
        v = make_float4(t[0], t[1], t[2], t[3]);
      } else {
        v = *(const float4*)(in1 + ((size_t)(b * IN1C + gc) << 14) + p0 + pxS);
      }
      *(float4*)&Xs[cS][pxS] = v;
#pragma unroll
      for (int j = 0; j < 8; ++j)
        Wt[cS][ocS + j] = Wm[(ocS + j) * CIN + cc + cS];
    }
    __syncthreads();
#pragma unroll
    for (int c = 0; c < 16; ++c) {
      float4 wv = *(const float4*)&Wt[c][ty * 4];
      float4 x0 = *(const float4*)&Xs[c][tx * 8];
      float4 x1 = *(const float4*)&Xs[c][tx * 8 + 4];
      float xs[8] = {x0.x, x0.y, x0.z, x0.w, x1.x, x1.y, x1.z, x1.w};
      float wf[4] = {wv.x, wv.y, wv.z, wv.w};
#pragma unroll
      for (int i = 0; i < 4; ++i)
#pragma unroll
        for (int j = 0; j < 8; ++j)
          acc[i][j] = fmaf(wf[i], xs[j], acc[i][j]);
    }
  }

#pragma unroll
  for (int i = 0; i < 4; ++i) {
    int oc = ty * 4 + i;
    size_t base = ((size_t)(b * 128 + oc) << 14) + p0 + tx * 8;
    float r[8];
#pragma unroll
    for (int j = 0; j < 8; ++j) r[j] = relu_(acc[i][j]);
    if (MODE == 2) {
#pragma unroll
      for (int j = 0; j < 8; ++j) r[j] += in2[base + j];
    }
    *(float4*)(out + base)     = make_float4(r[0], r[1], r[2], r[3]);
    *(float4*)(out + base + 4) = make_float4(r[4], r[5], r[6], r[7]);
  }
}

// ---------------------------------------------------------------------------
// t2h2: fused transpose of feat_l and feat_s: [b][128][HW] f32 -> [b][HW][128] f16
// ---------------------------------------------------------------------------
__global__ __launch_bounds__(256) void t2h2_kernel(
    const float* __restrict__ fl, const float* __restrict__ fs,
    _Float16* __restrict__ flTh, _Float16* __restrict__ fsTh)
{
  const int bx = blockIdx.x;
  const float* src;
  _Float16* dst;
  int HW, p0;
  if (bx < 512) { src = fl; dst = flTh; HW = 16384; p0 = bx * 32; }
  else          { src = fs; dst = fsTh; HW = 4096;  p0 = (bx - 512) * 32; }
  const int b  = blockIdx.z;
  const int c0 = blockIdx.y * 32;
  const int tid = threadIdx.x;
  __shared__ float T[32][33];
  {
    int pxl = tid & 31, cy = tid >> 5;
#pragma unroll
    for (int j = 0; j < 4; ++j) {
      int c = cy + j * 8;
      T[c][pxl] = src[((size_t)(b * 128 + c0 + c)) * HW + p0 + pxl];
    }
  }
  __syncthreads();
  {
    int cq = tid & 7, pr = tid >> 3;
    f16x4 v;
#pragma unroll
    for (int e = 0; e < 4; ++e) v[e] = (_Float16)T[cq * 4 + e][pr];
    *(f16x4*)&dst[(((size_t)b * HW) + p0 + pr) * 128 + c0 + cq * 4] = v;
  }
}

// ---------------------------------------------------------------------------
// t2hg: re-layout fsTh [b][y*64+x][128ch] -> fsThg [b][g][y][x][16ch] (f16).
// One f16x8 per thread; 131,072 threads = 512 blocks. ~4 MB traffic.
// ---------------------------------------------------------------------------
__global__ __launch_bounds__(256) void t2hg_kernel(
    const _Float16* __restrict__ fsTh, _Float16* __restrict__ fsThg)
{
  const int u = blockIdx.x * 256 + threadIdx.x;   // 131,072 total
  const int half = u & 1;
  const int x = (u >> 1) & 63;
  const int y = (u >> 7) & 63;
  const int g = (u >> 13) & 7;
  const int b = u >> 16;
  f16x8 v = *(const f16x8*)&fsTh[(((size_t)b << 12) + (y << 6) + x) * 128 + g * 16 + half * 8];
  ((f16x8*)fsThg)[u] = v;
}

// ---------------------------------------------------------------------------
// wfall: all 5 weight packs in one launch. Block ranges:
// [0,8) WfA | [8,24) WfB | [24,168) WfP | [168,204) Wf2 | [204,208) WfC
// ---------------------------------------------------------------------------
__global__ __launch_bounds__(256) void wfall_kernel(
    const float* __restrict__ fsm_w, const float* __restrict__ offset_w,
    const float* __restrict__ com_w, const float* __restrict__ dcn_w,
    const float* __restrict__ cat_w,
    _Float16* __restrict__ WfA, _Float16* __restrict__ WfB,
    _Float16* __restrict__ WfP, _Float16* __restrict__ Wf2,
    _Float16* __restrict__ WfC)
{
  const int bid = blockIdx.x;
  if (bid < 8) {                         // WfA: fsm_w [128][128]
    int idx = bid * 256 + threadIdx.x;
    int lane = idx & 63;
    int t = idx >> 6;
    int m = t & 7, q = t >> 3;
    int oc = m * 16 + (lane & 15);
    int c0 = q * 32 + (lane >> 4) * 8;
    f16x8 v;
#pragma unroll
    for (int j = 0; j < 8; ++j) v[j] = (_Float16)fsm_w[oc * 128 + c0 + j];
    ((f16x8*)WfA)[idx] = v;
  } else if (bid < 24) {                 // WfB: offset_w [128][256], x2 on c>=128
    int idx = (bid - 8) * 256 + threadIdx.x;
    int lane = idx & 63;
    int t = idx >> 6;
    int m = t & 7, q = t >> 3;
    int oc = m * 16 + (lane & 15);
    int c0 = q * 32 + (lane >> 4) * 8;
    float s = (q >= 4) ? 2.f : 1.f;
    f16x8 v;
#pragma unroll
    for (int j = 0; j < 8; ++j) v[j] = (_Float16)(offset_w[oc * 256 + c0 + j] * s);
    ((f16x8*)WfB)[idx] = v;
  } else if (bid < 168) {                // WfP: com_w, oc-half-major, pad 256
    int idx = (bid - 24) * 256 + threadIdx.x;
    int lane = idx & 63;
    int t = idx >> 6;
    int m = t & 7;
    int t2 = t >> 3;
    int half = t2 & 1, q = t2 >> 1;
    int kk = q >> 2;
    int ic0 = (q & 3) * 32 + (lane >> 4) * 8;
    int oc = half * 128 + m * 16 + (lane & 15);
    f16x8 v;
#pragma unroll
    for (int j = 0; j < 8; ++j) {
      float x = (oc < 216) ? com_w[((size_t)oc * 128 + ic0 + j) * 9 + kk] : 0.f;
      v[j] = (_Float16)x;
    }
    ((f16x8*)WfP)[idx] = v;
  } else if (bid < 204) {                // Wf2: dcn_w, r' = (g*9+k)*16+c
    int idx = (bid - 168) * 256 + threadIdx.x;
    int lane = idx & 63;
    int t = idx >> 6;
    int m = t & 3, q = t >> 2;
    int oc = m * 16 + (lane & 15);
    f16x8 v;
#pragma unroll
    for (int j = 0; j < 8; ++j) {
      int rp = q * 32 + (lane >> 4) * 8 + j;
      int c = rp & 15, tt = rp >> 4;
      int g = tt / 9, k = tt % 9;
      v[j] = (_Float16)dcn_w[((size_t)oc * 128 + g * 16 + c) * 9 + k];
    }
    ((f16x8*)Wf2)[idx] = v;
  } else {                               // WfC: cat_w [128][64]
    int idx = (bid - 204) * 256 + threadIdx.x;
    int lane = idx & 63;
    int t = idx >> 6;
    int m = t & 7, q = t >> 3;
    int oc = m * 16 + (lane & 15);
    int k0 = q * 32 + (lane >> 4) * 8;
    f16x8 v;
#pragma unroll
    for (int j = 0; j < 8; ++j) v[j] = (_Float16)cat_w[oc * 64 + k0 + j];
    ((f16x8*)WfC)[idx] = v;
  }
}

// ---------------------------------------------------------------------------
// fsm GEMM: arm = relu(fsm_w @ feat_l). Outputs arm f32 [oc][p] + armh f16 [p][oc].
// ---------------------------------------------------------------------------
__global__ __launch_bounds__(256) void fsm_gemm_kernel(
    const _Float16* __restrict__ flTh, const _Float16* __restrict__ WfA,
    float* __restrict__ arm, _Float16* __restrict__ armh)
{
  const int b    = blockIdx.y;
  const int tid  = threadIdx.x;
  const int wv   = tid >> 6;
  const int lane = tid & 63;
  const int px0  = blockIdx.x * 64 + wv * 16;
  const int pxl  = px0 + (lane & 15);

  f32x4 acc[8];
#pragma unroll
  for (int m = 0; m < 8; ++m) acc[m] = (f32x4){0.f, 0.f, 0.f, 0.f};

  const f16x8* Bp = (const f16x8*)flTh + (((size_t)b << 14) + pxl) * 16 + (lane >> 4);
  const f16x8* Ap = (const f16x8*)WfA + lane;

#pragma unroll
  for (int q = 0; q < 4; ++q) {
    f16x8 bf = Bp[q * 4];
#pragma unroll
    for (int m = 0; m < 8; ++m)
      acc[m] = __builtin_amdgcn_mfma_f32_16x16x32_f16(Ap[(q * 8 + m) * 64], bf, acc[m], 0, 0, 0);
  }

  const int r0 = (lane >> 4) * 4;
#pragma unroll
  for (int m = 0; m < 8; ++m) {
    f16x4 h;
#pragma unroll
    for (int r = 0; r < 4; ++r) {
      float v = relu_(acc[m][r]);
      arm[((size_t)(b * 128 + m * 16 + r0 + r) << 14) + pxl] = v;
      h[r] = (_Float16)v;
    }
    *(f16x4*)&armh[(((size_t)b << 14) + pxl) * 128 + m * 16 + r0] = h;
  }
}

// ---------------------------------------------------------------------------
// offset GEMM: offh = relu(offset_w @ [armh ; 2*featup]) in f16 [p][128].
// ---------------------------------------------------------------------------
__global__ __launch_bounds__(256) void off_gemm_kernel(
    const _Float16* __restrict__ armh, const _Float16* __restrict__ fsTh,
    const _Float16* __restrict__ WfB, _Float16* __restrict__ offh)
{
  const int b    = blockIdx.y;
  const int tid  = threadIdx.x;
  const int wv   = tid >> 6;
  const int lane = tid & 63;
  const int px0  = blockIdx.x * 64 + wv * 16;
  const int pxl  = px0 + (lane & 15);
  const int h = pxl >> 7, w = pxl & 127;
  const int pup = ((h >> 1) << 6) + (w >> 1);

  f32x4 acc[8];
#pragma unroll
  for (int m = 0; m < 8; ++m) acc[m] = (f32x4){0.f, 0.f, 0.f, 0.f};

  const f16x8* BpA = (const f16x8*)armh + (((size_t)b << 14) + pxl) * 16 + (lane >> 4);
  const f16x8* BpU = (const f16x8*)fsTh + (((size_t)b << 12) + pup) * 16 + (lane >> 4);
  const f16x8* Ap  = (const f16x8*)WfB + lane;

#pragma unroll
  for (int q = 0; q < 8; ++q) {
    f16x8 bf = (q < 4) ? BpA[q * 4] : BpU[(q - 4) * 4];
#pragma unroll
    for (int m = 0; m < 8; ++m)
      acc[m] = __builtin_amdgcn_mfma_f32_16x16x32_f16(Ap[(q * 8 + m) * 64], bf, acc[m], 0, 0, 0);
  }

  const int r0 = (lane >> 4) * 4;
#pragma unroll
  for (int m = 0; m < 8; ++m) {
    f16x4 hh;
#pragma unroll
    for (int r = 0; r < 4; ++r) hh[r] = (_Float16)relu_(acc[m][r]);
    *(f16x4*)&offh[(((size_t)b << 14) + pxl) * 128 + m * 16 + r0] = hh;
  }
}

// ---------------------------------------------------------------------------
// com GEMM (LDS-staged, depth-2 B prefetch): omh f16 [b][oc][p], oc padded 256.
// ---------------------------------------------------------------------------
__global__ __launch_bounds__(256) void com_gemm_kernel(
    const _Float16* __restrict__ offh, const _Float16* __restrict__ WfP,
    const float* __restrict__ cb, _Float16* __restrict__ omh)
{
  const int b    = blockIdx.z;
  const int half = blockIdx.y;
  const int tid  = threadIdx.x;
  const int lane = tid & 63;
  const int px0  = blockIdx.x * 64 + (tid >> 6) * 16;
  const int pxl  = px0 + (lane & 15);
  const int h = pxl >> 7, w = pxl & 127;

  __shared__ f16x8 As[512];   // 8 KB

  f32x4 acc[8];
#pragma unroll
  for (int m = 0; m < 8; ++m) acc[m] = (f32x4){0.f, 0.f, 0.f, 0.f};

  const f16x8* Bbase = (const f16x8*)offh + ((size_t)b << 14) * 16 + (lane >> 4);
  const f16x8* Wp    = (const f16x8*)WfP + half * 512 + tid * 2;
  const f16x8 zero = {(_Float16)0.f, (_Float16)0.f, (_Float16)0.f, (_Float16)0.f,
                      (_Float16)0.f, (_Float16)0.f, (_Float16)0.f, (_Float16)0.f};

  auto loadB = [&](int t) -> f16x8 {
    const int kk = t >> 2, ic4 = t & 3;
    const int hh = h + kk / 3 - 1;
    const int ww = w + kk % 3 - 1;
    const bool valid = ((unsigned)hh < 128u) && ((unsigned)ww < 128u);
    const int ps = valid ? ((hh << 7) + ww) : 0;
    f16x8 bf = Bbase[(size_t)ps * 16 + ic4 * 4];
    return valid ? bf : zero;
  };

  f16x8 rA0 = Wp[0], rA1 = Wp[1];
  f16x8 bfA = loadB(0), bfB = loadB(1);

#pragma unroll 1
  for (int tt = 0; tt < 18; ++tt) {
    const int t0 = tt * 2;
    __syncthreads();
    As[tid * 2] = rA0; As[tid * 2 + 1] = rA1;
    __syncthreads();
    rA0 = Wp[(t0 + 1) * 1024]; rA1 = Wp[(t0 + 1) * 1024 + 1];
    {
      f16x8 bu = bfA;
      if (t0 + 2 < 36) bfA = loadB(t0 + 2);
#pragma unroll
      for (int m = 0; m < 8; ++m)
        acc[m] = __builtin_amdgcn_mfma_f32_16x16x32_f16(As[m * 64 + lane], bu, acc[m], 0, 0, 0);
    }
    __syncthreads();
    As[tid * 2] = rA0; As[tid * 2 + 1] = rA1;
    __syncthreads();
    if (t0 + 2 < 36) { rA0 = Wp[(t0 + 2) * 1024]; rA1 = Wp[(t0 + 2) * 1024 + 1]; }
    {
      f16x8 bu = bfB;
      if (t0 + 3 < 36) bfB = loadB(t0 + 3);
#pragma unroll
      for (int m = 0; m < 8; ++m)
        acc[m] = __builtin_amdgcn_mfma_f32_16x16x32_f16(As[m * 64 + lane], bu, acc[m], 0, 0, 0);
    }
  }

  const int r0i = (lane >> 4) * 4;
#pragma unroll
  for (int m = 0; m < 8; ++m) {
#pragma unroll
    for (int r = 0; r < 4; ++r) {
      int oc = half * 128 + m * 16 + r0i + r;
      if (oc < 216)
        omh[((size_t)(b * 216 + oc) << 14) + pxl] = (_Float16)(acc[m][r] + cb[oc]);
    }
  }
}

// ---------------------------------------------------------------------------
// dcn FUSED kernel (group-major fsThg layout): bilinear sampling + masked
// einsum in one pass. Wave = 16 px x 64 oc, K = 1152 in 36 chunks.
// Tap = 16B at fsThg[(g<<16) + (y>>1)<<10 + (x>>1)<<4 + chalf] -- a wave's
// 16-px strip hits ~5-6 contiguous 64B lines per tap (vs ~16 scattered in
// the [px][128ch] layout). Arithmetic identical to round 10.
// ---------------------------------------------------------------------------
__global__ __launch_bounds__(256) void dcn_fused_kernel(
    const _Float16* __restrict__ fsThg, const _Float16* __restrict__ omh,
    const _Float16* __restrict__ Wf2, const float* __restrict__ db,
    _Float16* __restrict__ alh)
{
  const int b    = blockIdx.y;
  const int tid  = threadIdx.x;
  const int wv   = tid >> 6;
  const int lane = tid & 63;
  const int px0  = blockIdx.x * 64 + wv * 16;
  const int pxl  = px0 + (lane & 15);
  const int h = pxl >> 7, w = pxl & 127;
  const int t9add = lane >> 5;             // 0 or 1
  const int chalf = ((lane >> 4) & 1) << 3; // 0 or 8

  const _Float16* omp = omh + (((size_t)b * 216) << 14) + pxl;
  const _Float16* fb = fsThg + ((size_t)b << 19);
  const f16x8* Ap = (const f16x8*)Wf2 + lane;

  f32x4 acc[4];
#pragma unroll
  for (int m = 0; m < 4; ++m) acc[m] = (f32x4){0.f, 0.f, 0.f, 0.f};

#pragma unroll 1
  for (int q = 0; q < 36; ++q) {
    const int t9 = 2 * q + t9add;
    const int g = t9 / 9;
    const int k = t9 - g * 9;

    const float offy = (float)omp[(size_t)(g * 18 + 2 * k) << 14];
    const float offx = (float)omp[(size_t)(g * 18 + 2 * k + 1) << 14];
    const float mraw = (float)omp[(size_t)(144 + t9) << 14];
    const float mv = 1.f / (1.f + __expf(-mraw));

    const float py  = (float)(h + k / 3 - 1) + offy;
    const float pxx = (float)(w + k % 3 - 1) + offx;
    const float y0f = floorf(py), x0f = floorf(pxx);
    const float ly = py - y0f, lx = pxx - x0f;
    const int y0 = (int)y0f, x0i = (int)x0f;
    const int y1 = y0 + 1, x1 = x0i + 1;

    const int y0c = min(max(y0, 0), 127), y1c = min(max(y1, 0), 127);
    const int x0c = min(max(x0i, 0), 127), x1c = min(max(x1, 0), 127);

    float w00 = (1.f - ly) * (1.f - lx) * mv;
    float w01 = (1.f - ly) * lx * mv;
    float w10 = ly * (1.f - lx) * mv;
    float w11 = ly * lx * mv;
    const bool vy0 = (unsigned)y0 < 128u, vy1 = (unsigned)y1 < 128u;
    const bool vx0 = (unsigned)x0i < 128u, vx1 = (unsigned)x1 < 128u;
    w00 = (vy0 && vx0) ? w00 : 0.f;
    w01 = (vy0 && vx1) ? w01 : 0.f;
    w10 = (vy1 && vx0) ? w10 : 0.f;
    w11 = (vy1 && vx1) ? w11 : 0.f;

    const int gb = (g << 16) + chalf;
    const int a00 = gb + ((y0c >> 1) << 10) + ((x0c >> 1) << 4);
    const int a01 = gb + ((y0c >> 1) << 10) + ((x1c >> 1) << 4);
    const int a10 = gb + ((y1c >> 1) << 10) + ((x0c >> 1) << 4);
    const int a11 = gb + ((y1c >> 1) << 10) + ((x1c >> 1) << 4);

    f16x8 t00 = *(const f16x8*)(fb + a00);
    f16x8 t01 = *(const f16x8*)(fb + a01);
    f16x8 t10 = *(const f16x8*)(fb + a10);
    f16x8 t11 = *(const f16x8*)(fb + a11);

    f16x8 bf;
#pragma unroll
    for (int j = 0; j < 8; ++j)
      bf[j] = (_Float16)(w00 * (float)t00[j] + w01 * (float)t01[j]
                       + w10 * (float)t10[j] + w11 * (float)t11[j]);

    const f16x8* ap = Ap + q * 256;
#pragma unroll
    for (int m = 0; m < 4; ++m)
      acc[m] = __builtin_amdgcn_mfma_f32_16x16x32_f16(ap[m * 64], bf, acc[m], 0, 0, 0);
  }

  const int r0 = (lane >> 4) * 4;
#pragma unroll
  for (int m = 0; m < 4; ++m) {
    f16x4 hv;
#pragma unroll
    for (int r = 0; r < 4; ++r) {
      int oc = m * 16 + r0 + r;
      hv[r] = (_Float16)relu_(acc[m][r] + db[oc]);
    }
    *(f16x4*)&alh[(((size_t)b << 14) + pxl) * 64 + m * 16 + r0] = hv;
  }
}

// ---------------------------------------------------------------------------
// cat GEMM: out[b][oc][p] = relu(cat_w @ feat_align) + arm. K=64 (2 chunks).
// ---------------------------------------------------------------------------
__global__ __launch_bounds__(256) void cat_gemm_kernel(
    const _Float16* __restrict__ alh, const _Float16* __restrict__ WfC,
    const float* __restrict__ arm, float* __restrict__ out)
{
  const int b    = blockIdx.y;
  const int tid  = threadIdx.x;
  const int wv   = tid >> 6;
  const int lane = tid & 63;
  const int px0  = blockIdx.x * 64 + wv * 16;
  const int pxl  = px0 + (lane & 15);

  f32x4 acc[8];
#pragma unroll
  for (int m = 0; m < 8; ++m) acc[m] = (f32x4){0.f, 0.f, 0.f, 0.f};

  const f16x8* Bp = (const f16x8*)alh + (((size_t)b << 14) + pxl) * 8 + (lane >> 4);
  const f16x8* Ap = (const f16x8*)WfC + lane;

#pragma unroll
  for (int q = 0; q < 2; ++q) {
    f16x8 bf = Bp[q * 4];
#pragma unroll
    for (int m = 0; m < 8; ++m)
      acc[m] = __builtin_amdgcn_mfma_f32_16x16x32_f16(Ap[(q * 8 + m) * 64], bf, acc[m], 0, 0, 0);
  }

  const int r0 = (lane >> 4) * 4;
#pragma unroll
  for (int m = 0; m < 8; ++m) {
#pragma unroll
    for (int r = 0; r < 4; ++r) {
      int oc = m * 16 + r0 + r;
      size_t a = ((size_t)(b * 128 + oc) << 14) + pxl;
      out[a] = relu_(acc[m][r]) + arm[a];
    }
  }
}

// ---------------------------------------------------------------------------
// FALLBACK path kernels (small ws): round-1 versions
// ---------------------------------------------------------------------------
__global__ __launch_bounds__(256) void com_conv_kernel(
    const float* __restrict__ x, const float* __restrict__ cw,
    const float* __restrict__ cb, float* __restrict__ om)
{
  const int b    = blockIdx.z;
  const int ocg  = blockIdx.y;
  const int tile = blockIdx.x;
  const int th = (tile >> 2) * 32, tw = (tile & 3) * 32;
  const int tid = threadIdx.x;
  const int lw = (tid & 7) * 4;
  const int lh = tid >> 3;

  __shared__ float Xs[8 * 34 * 34];

  float acc[8][4];
#pragma unroll
  for (int a = 0; a < 8; ++a)
#pragma unroll
    for (int p = 0; p < 4; ++p) acc[a][p] = 0.f;

  for (int cc = 0; cc < 128; cc += 8) {
    __syncthreads();
    for (int idx = tid; idx < 8 * 1156; idx += 256) {
      int ic  = idx / 1156;
      int rem = idx - ic * 1156;
      int yy  = rem / 34;
      int xx  = rem - yy * 34;
      int gh = th + yy - 1, gw = tw + xx - 1;
      float v = 0.f;
      if ((unsigned)gh < 128u && (unsigned)gw < 128u)
        v = x[((size_t)(b * 128 + cc + ic) << 14) + (gh << 7) + gw];
      Xs[idx] = v;
    }
    __syncthreads();
#pragma unroll 1
    for (int ic = 0; ic < 8; ++ic) {
      float xr[3][6];
#pragma unroll
      for (int ky = 0; ky < 3; ++ky)
#pragma unroll
        for (int xx = 0; xx < 6; ++xx)
          xr[ky][xx] = Xs[ic * 1156 + (lh + ky) * 34 + lw + xx];
      const float* wp = cw + ((size_t)(ocg * 8) * 128 + (cc + ic)) * 9;
#pragma unroll
      for (int a = 0; a < 8; ++a) {
        const float* w9 = wp + a * 1152;
#pragma unroll
        for (int ky = 0; ky < 3; ++ky)
#pragma unroll
          for (int kx = 0; kx < 3; ++kx) {
            float wv = w9[ky * 3 + kx];
#pragma unroll
            for (int p = 0; p < 4; ++p)
              acc[a][p] = fmaf(wv, xr[ky][kx + p], acc[a][p]);
          }
      }
    }
  }

#pragma unroll
  for (int a = 0; a < 8; ++a) {
    int oc = ocg * 8 + a;
    float bv = cb[oc];
    float4 r = make_float4(acc[a][0] + bv, acc[a][1] + bv,
                           acc[a][2] + bv, acc[a][3] + bv);
    *(float4*)(om + ((size_t)(b * 216 + oc) << 14) + ((th + lh) << 7) + tw + lw) = r;
  }
}

__global__ __launch_bounds__(256) void wt_kernel(const float* __restrict__ dw,
                                                 float* __restrict__ wT)
{
  int idx = blockIdx.x * 256 + threadIdx.x;
  int o    = idx & 63;
  int rest = idx >> 6;
  int k    = rest % 9;
  int gc   = rest / 9;
  wT[idx] = dw[(o * 128 + gc) * 9 + k];
}

__global__ __launch_bounds__(256) void dcn_kernel(
    const float* __restrict__ fs, const float* __restrict__ om,
    const float* __restrict__ wT, const float* __restrict__ db,
    float* __restrict__ al)
{
  const int b   = blockIdx.y;
  const int p0  = blockIdx.x * 32;
  const int tid = threadIdx.x;
  const int px  = tid & 31;
  const int g   = tid >> 5;
  const int p = p0 + px;
  const int h = p >> 7, w = p & 127;

  float acc[64];
#pragma unroll
  for (int o = 0; o < 64; ++o) acc[o] = 0.f;

  const size_t omb = ((size_t)b * 216) << 14;
  const float* fsg = fs + (((size_t)(b * 128 + g * 16)) << 12);
  const float* wg  = wT + g * (16 * 9 * 64);

#pragma unroll 1
  for (int k = 0; k < 9; ++k) {
    float offy = om[omb + ((size_t)(g * 18 + 2 * k) << 14) + p];
    float offx = om[omb + ((size_t)(g * 18 + 2 * k + 1) << 14) + p];
    float mraw = om[omb + ((size_t)(144 + g * 9 + k) << 14) + p];
    float mv = 1.f / (1.f + __expf(-mraw));

    float py  = (float)(h + k / 3 - 1) + offy;
    float pxx = (float)(w + k % 3 - 1) + offx;
    float y0f = floorf(py), x0f = floorf(pxx);
    float ly = py - y0f, lx = pxx - x0f;
    int y0 = (int)y0f, x0i = (int)x0f;
    int y1 = y0 + 1, x1 = x0i + 1;

    int y0c = min(max(y0, 0), 127), y1c = min(max(y1, 0), 127);
    int x0c = min(max(x0i, 0), 127), x1c = min(max(x1, 0), 127);
    int ry0 = (y0c >> 1) << 6, ry1 = (y1c >> 1) << 6;
    int cx0 = x0c >> 1, cx1 = x1c >> 1;

    float w00 = (1.f - ly) * (1.f - lx) * mv;
    float w01 = (1.f - ly) * lx * mv;
    float w10 = ly * (1.f - lx) * mv;
    float w11 = ly * lx * mv;
    bool vy0 = (unsigned)y0 < 128u, vy1 = (unsigned)y1 < 128u;
    bool vx0 = (unsigned)x0i < 128u, vx1 = (unsigned)x1 < 128u;
    w00 = (vy0 && vx0) ? w00 : 0.f;
    w01 = (vy0 && vx1) ? w01 : 0.f;
    w10 = (vy1 && vx0) ? w10 : 0.f;
    w11 = (vy1 && vx1) ? w11 : 0.f;

#pragma unroll 1
    for (int c = 0; c < 16; ++c) {
      const float* fc = fsg + (c << 12);
      float v00 = fc[ry0 + cx0];
      float v01 = fc[ry0 + cx1];
      float v10 = fc[ry1 + cx0];
      float v11 = fc[ry1 + cx1];
      float v = w00 * v00 + w01 * v01 + w10 * v10 + w11 * v11;
      const float* wp = wg + (c * 9 + k) * 64;
#pragma unroll
      for (int oq = 0; oq < 16; ++oq) {
        float4 w4 = *(const float4*)(wp + oq * 4);
        acc[oq * 4 + 0] = fmaf(v, w4.x, acc[oq * 4 + 0]);
        acc[oq * 4 + 1] = fmaf(v, w4.y, acc[oq * 4 + 1]);
        acc[oq * 4 + 2] = fmaf(v, w4.z, acc[oq * 4 + 2]);
        acc[oq * 4 + 3] = fmaf(v, w4.w, acc[oq * 4 + 3]);
      }
    }
  }

  __shared__ float red[256][17];
  const int px2 = tid & 31;
  const int og  = tid >> 5;
#pragma unroll
  for (int r = 0; r < 4; ++r) {
    __syncthreads();
#pragma unroll
    for (int j = 0; j < 16; ++j) red[tid][j] = acc[r * 16 + j];
    __syncthreads();
#pragma unroll
    for (int jj = 0; jj < 2; ++jj) {
      int ol = og * 2 + jj;
      float s = 0.f;
#pragma unroll
      for (int gg = 0; gg < 8; ++gg) s += red[gg * 32 + px2][ol];
      int oc = r * 16 + ol;
      s += db[oc];
      al[((size_t)(b * 64 + oc) << 14) + p0 + px2] = fmaxf(s, 0.f);
    }
  }
}

// ---------------------------------------------------------------------------
extern "C" void kernel_launch(void* const* d_in, const int* in_sizes, int n_in,
                              void* d_out, int out_size, void* d_ws, size_t ws_size,
                              hipStream_t stream)
{
  const float* feat_l   = (const float*)d_in[0];
  const float* feat_s   = (const float*)d_in[1];
  const float* fsm_w    = (const float*)d_in[2];
  const float* offset_w = (const float*)d_in[3];
  const float* com_w    = (const float*)d_in[4];
  const float* com_b    = (const float*)d_in[5];
  const float* dcn_w    = (const float*)d_in[6];
  const float* dcn_b    = (const float*)d_in[7];
  const float* cat_w    = (const float*)d_in[8];
  float* out = (float*)d_out;
  float* ws  = (float*)d_ws;

  const size_t NEED = (size_t)(4194304 + 7077888 + 2097152 + 1048576 + 37748736) * 4;

  if (ws_size >= NEED) {
    float* arm      = ws;                          // 4,194,304 f32
    _Float16* omh   = (_Float16*)(ws + 4194304);   // 7,077,888 f16
    _Float16* alh   = (_Float16*)(ws + 11272192);  // 2,097,152 f16
    _Float16* Wf2   = (_Float16*)(ws + 12320768);  // 73,728 f16
    _Float16* WfC   = (_Float16*)(ws + 12357632);  // 8,192 f16
    _Float16* fsTh  = (_Float16*)(ws + 13369344);  // 1,048,576 f16
    _Float16* flTh  = (_Float16*)(ws + 13893632);  // 4,194,304 f16
    _Float16* armh  = (_Float16*)(ws + 15990784);  // 4,194,304 f16
    _Float16* offh  = (_Float16*)(ws + 18087936);  // 4,194,304 f16
    _Float16* WfA   = (_Float16*)(ws + 39059456);  // 16,384 f16
    _Float16* WfB   = (_Float16*)(ws + 39067648);  // 32,768 f16
    _Float16* WfP   = (_Float16*)(ws + 39084032);  // 294,912 f16 (ends 39,231,488 fl)
    _Float16* fsThg = (_Float16*)(ws + 39231488);  // 1,048,576 f16 (ends 39,755,776 fl)

    hipLaunchKernelGGL(wfall_kernel, dim3(208), dim3(256), 0, stream,
                       fsm_w, offset_w, com_w, dcn_w, cat_w, WfA, WfB, WfP, Wf2, WfC);
    hipLaunchKernelGGL(t2h2_kernel, dim3(640, 4, 2), dim3(256), 0, stream,
                       feat_l, feat_s, flTh, fsTh);
    hipLaunchKernelGGL(t2hg_kernel, dim3(512), dim3(256), 0, stream,
                       fsTh, fsThg);
    hipLaunchKernelGGL(fsm_gemm_kernel, dim3(256, 2), dim3(256), 0, stream,
                       flTh, WfA, arm, armh);
    hipLaunchKernelGGL(off_gemm_kernel, dim3(256, 2), dim3(256), 0, stream,
                       armh, fsTh, WfB, offh);
    hipLaunchKernelGGL(com_gemm_kernel, dim3(256, 2, 2), dim3(256), 0, stream,
                       offh, WfP, com_b, omh);
    hipLaunchKernelGGL(dcn_fused_kernel, dim3(256, 2), dim3(256), 0, stream,
                       fsThg, omh, Wf2, dcn_b, alh);
    hipLaunchKernelGGL(cat_gemm_kernel, dim3(256, 2), dim3(256), 0, stream,
                       alh, WfC, arm, out);
  } else {
    float* arm = ws;
    float* off = ws + 4194304;
    float* om  = ws + 8388608;
    float* al  = ws + 15466496;
    float* wT  = ws + 17563648;

    hipLaunchKernelGGL(wt_kernel, dim3(288), dim3(256), 0, stream, dcn_w, wT);
    hipLaunchKernelGGL((conv1x1_kernel<0, 128>), dim3(256, 2), dim3(256), 0, stream,
                       feat_l, nullptr, fsm_w, arm);
    hipLaunchKernelGGL((conv1x1_kernel<1, 256>), dim3(256, 2), dim3(256), 0, stream,
                       arm, feat_s, offset_w, off);
    hipLaunchKernelGGL(com_conv_kernel, dim3(16, 27, 2), dim3(256), 0, stream,
                       off, com_w, com_b, om);
    hipLaunchKernelGGL(dcn_kernel, dim3(512, 2), dim3(256), 0, stream,
                       feat_s, om, wT, dcn_b, al);
    hipLaunchKernelGGL((conv1x1_kernel<2, 64>), dim3(256, 2), dim3(256), 0, stream,
                       al, arm, cat_w, out);
  }
}